// Round 1
// baseline (23746.312 us; speedup 1.0000x reference)
//
#include <hip/hip_runtime.h>
#include <hip/hip_bf16.h>

#define HDIM 1024
#define BDIM 32
#define TDIM 64
#define SDIM 64
#define NL   2

__device__ __forceinline__ float sigm(float x){ return 1.f/(1.f+expf(-x)); }

// ---------------- init: copy h0,c0 into workspace state ----------------
__global__ void init_state_kernel(const float* __restrict__ h0,
                                  const float* __restrict__ c0,
                                  float* __restrict__ st){
  int i = blockIdx.x*256 + threadIdx.x;
  int n = NL*BDIM*HDIM;
  if(i < n) st[i] = h0[i];
  else if(i < 2*n) st[i] = c0[i-n];
}

// ---------------- embedding gather ----------------
__global__ void embed_kernel(const int* __restrict__ tokens,
                             const float* __restrict__ emb,
                             float* __restrict__ X){
  int tb = blockIdx.x;
  int tok = tokens[tb];
  const float4* src = (const float4*)(emb + (size_t)tok*HDIM);
  float4* dst = (float4*)(X + (size_t)tb*HDIM);
  dst[threadIdx.x] = src[threadIdx.x];
}

// ---------------- generic tiled GEMM: C = [Cinit +] A@B^T [+ bias1 + bias2], opt tanh
// A: [M,K] lda ; Bm: [N,K] ldb ; C: [M,N] ldc
template<int BM,int BN,int BK,int TM,int TN>
__global__ void gemm_bt(const float* __restrict__ A, int lda,
                        const float* __restrict__ Bm, int ldb,
                        const float* __restrict__ Cinit,
                        float* __restrict__ C, int ldc,
                        const float* __restrict__ bias1,
                        const float* __restrict__ bias2,
                        int M, int N, int K, int act){
  __shared__ float As[BK][BM+1];
  __shared__ float Bs[BK][BN+1];
  const int bm = blockIdx.y*BM, bn = blockIdx.x*BN;
  const int tid = threadIdx.x;                 // 256 threads
  const int tcol = tid % (BN/TN);
  const int trow = tid / (BN/TN);
  float acc[TM][TN];
  #pragma unroll
  for(int i=0;i<TM;i++)
    #pragma unroll
    for(int j=0;j<TN;j++) acc[i][j]=0.f;

  for(int k0=0;k0<K;k0+=BK){
    for(int i=tid;i<BM*BK;i+=256){
      int kk = i % BK, m = i / BK;
      int gm = bm+m;
      As[kk][m] = (gm<M) ? A[(size_t)gm*lda + k0+kk] : 0.f;
    }
    for(int i=tid;i<BN*BK;i+=256){
      int kk = i % BK, n = i / BK;
      Bs[kk][n] = Bm[(size_t)(bn+n)*ldb + k0+kk];
    }
    __syncthreads();
    #pragma unroll
    for(int kk=0;kk<BK;kk++){
      float a[TM], b[TN];
      #pragma unroll
      for(int i=0;i<TM;i++) a[i]=As[kk][trow*TM+i];
      #pragma unroll
      for(int j=0;j<TN;j++) b[j]=Bs[kk][tcol*TN+j];
      #pragma unroll
      for(int i=0;i<TM;i++)
        #pragma unroll
        for(int j=0;j<TN;j++) acc[i][j] += a[i]*b[j];
    }
    __syncthreads();
  }
  #pragma unroll
  for(int i=0;i<TM;i++){
    int gm = bm + trow*TM + i;
    if(gm >= M) continue;
    #pragma unroll
    for(int j=0;j<TN;j++){
      int gn = bn + tcol*TN + j;
      float v = acc[i][j];
      if(Cinit) v += Cinit[(size_t)gm*ldc + gn];
      if(bias1) v += bias1[gn];
      if(bias2) v += bias2[gn];
      if(act==1) v = tanhf(v);
      C[(size_t)gm*ldc + gn] = v;
    }
  }
}

// ---------------- LSTM cell elementwise ----------------
__global__ void lstm_cell_kernel(const float* __restrict__ gates, // [B,4H]
                                 float* __restrict__ h, float* __restrict__ c,
                                 float* __restrict__ inp_all_t){   // may be null
  int idx = blockIdx.x*256 + threadIdx.x;      // 0..B*H-1
  int b = idx >> 10, j = idx & (HDIM-1);
  const float* gr = gates + (size_t)b*4*HDIM;
  float gi = gr[j], gf = gr[j+HDIM], gg = gr[j+2*HDIM], go = gr[j+3*HDIM];
  float cc = c[idx];
  float c1 = sigm(gf)*cc + sigm(gi)*tanhf(gg);
  float h1 = sigm(go)*tanhf(c1);
  c[idx] = c1; h[idx] = h1;
  if(inp_all_t) inp_all_t[idx] = h1;
}

// ---------------- attention: scores -> softmax -> ctx ----------------
__global__ void attn_kernel(const float* __restrict__ gamma,    // [T*B, H]
                            const float* __restrict__ contexts, // [B, S, H]
                            float* __restrict__ ctxout){        // [T*B, H]
  int tb = blockIdx.x;
  int b = tb & (BDIM-1);
  const float* g  = gamma + (size_t)tb*HDIM;
  const float* cb = contexts + (size_t)b*SDIM*HDIM;
  __shared__ float sc[SDIM];
  __shared__ float wexp[SDIM];
  __shared__ float red[256];
  int tid = threadIdx.x;
  int s = tid >> 2, q = tid & 3;
  float p = 0.f;
  const float* row = cb + (size_t)s*HDIM;
  for(int k=q*256;k<q*256+256;k++) p += g[k]*row[k];
  red[tid] = p;
  __syncthreads();
  if(q==0) sc[s] = red[tid]+red[tid+1]+red[tid+2]+red[tid+3];
  __syncthreads();
  float mx = -1e30f;
  for(int s2=0;s2<SDIM;s2++) mx = fmaxf(mx, sc[s2]);
  if(tid < SDIM) wexp[tid] = expf(sc[tid]-mx);
  __syncthreads();
  float sum = 0.f;
  for(int s2=0;s2<SDIM;s2++) sum += wexp[s2];
  float inv = 1.f/sum;
  for(int hh=tid; hh<HDIM; hh+=256){
    float a = 0.f;
    for(int s2=0;s2<SDIM;s2++) a += wexp[s2]*cb[(size_t)s2*HDIM + hh];
    ctxout[(size_t)tb*HDIM + hh] = a*inv;
  }
}

// ---------------- final state copy ----------------
__global__ void copy_state_kernel(const float* __restrict__ st, float* __restrict__ dst){
  int i = blockIdx.x*256 + threadIdx.x;
  if(i < 2*NL*BDIM*HDIM) dst[i] = st[i];
}

extern "C" void kernel_launch(void* const* d_in, const int* in_sizes, int n_in,
                              void* d_out, int out_size, void* d_ws, size_t ws_size,
                              hipStream_t stream){
  const int*   tokens   = (const int*)  d_in[0];
  const float* h0       = (const float*)d_in[1];
  const float* c0       = (const float*)d_in[2];
  const float* contexts = (const float*)d_in[3];
  const float* emb      = (const float*)d_in[4];
  const float* W_ih     = (const float*)d_in[5];   // [2,4H,H]
  const float* W_hh     = (const float*)d_in[6];
  const float* b_ih     = (const float*)d_in[7];   // [2,4H]
  const float* b_hh     = (const float*)d_in[8];
  const float* W_in     = (const float*)d_in[9];   // [H,H]
  const float* b_in     = (const float*)d_in[10];
  const float* W_out    = (const float*)d_in[11];  // [H,2H]
  const float* b_out    = (const float*)d_in[12];

  float* out = (float*)d_out;
  float* ws  = (float*)d_ws;

  const int TB = TDIM*BDIM;              // 2048
  // workspace layout (floats)
  float* state   = ws;                   // h [2,32,1024] then c [2,32,1024] = 131072
  float* state_h = state;
  float* state_c = state + NL*BDIM*HDIM;
  float* X       = ws + 131072;                        // [2048,1024]
  float* G0      = X + (size_t)TB*HDIM;                // [2048,4096]
  float* inp_all = G0 + (size_t)TB*4*HDIM;             // [2048,1024]
  float* gammaB  = inp_all + (size_t)TB*HDIM;          // [2048,1024]
  float* ctxB    = gammaB + (size_t)TB*HDIM;           // [2048,1024]
  float* gates0  = ctxB + (size_t)TB*HDIM;             // [32,4096]
  float* gates1  = gates0 + (size_t)BDIM*4*HDIM;       // [32,4096]

  const float* Wih0 = W_ih;
  const float* Wih1 = W_ih + (size_t)4*HDIM*HDIM;
  const float* Whh0 = W_hh;
  const float* Whh1 = W_hh + (size_t)4*HDIM*HDIM;

  // init state + embed
  init_state_kernel<<<512,256,0,stream>>>(h0, c0, state);
  embed_kernel<<<TB,256,0,stream>>>(tokens, emb, X);

  // G0 = X @ Wih0^T + b_ih0 + b_hh0   [2048,4096]
  gemm_bt<64,64,16,4,4><<<dim3(4*HDIM/64, TB/64),256,0,stream>>>(
      X, HDIM, Wih0, HDIM, nullptr, G0, 4*HDIM, b_ih, b_hh, TB, 4*HDIM, HDIM, 0);

  for(int t=0;t<TDIM;t++){
    float* h0s = state_h;                 // layer 0 h
    float* c0s = state_c;
    float* h1s = state_h + BDIM*HDIM;     // layer 1 h
    float* c1s = state_c + BDIM*HDIM;
    // layer 0: gates0 = G0[t] + h0 @ Whh0^T
    gemm_bt<32,64,16,2,4><<<dim3(4*HDIM/64,1),256,0,stream>>>(
        h0s, HDIM, Whh0, HDIM, G0 + (size_t)t*BDIM*4*HDIM, gates0, 4*HDIM,
        nullptr, nullptr, BDIM, 4*HDIM, HDIM, 0);
    lstm_cell_kernel<<<BDIM*HDIM/256,256,0,stream>>>(gates0, h0s, c0s, nullptr);
    // layer 1: gates1 = h0_new @ Wih1^T + b_ih1 + b_hh1
    gemm_bt<32,64,16,2,4><<<dim3(4*HDIM/64,1),256,0,stream>>>(
        h0s, HDIM, Wih1, HDIM, nullptr, gates1, 4*HDIM,
        b_ih + 4*HDIM, b_hh + 4*HDIM, BDIM, 4*HDIM, HDIM, 0);
    //           gates1 += h1 @ Whh1^T
    gemm_bt<32,64,16,2,4><<<dim3(4*HDIM/64,1),256,0,stream>>>(
        h1s, HDIM, Whh1, HDIM, gates1, gates1, 4*HDIM,
        nullptr, nullptr, BDIM, 4*HDIM, HDIM, 0);
    lstm_cell_kernel<<<BDIM*HDIM/256,256,0,stream>>>(gates1, h1s, c1s,
        inp_all + (size_t)t*BDIM*HDIM);
  }

  // gamma = inp_all @ W_in^T + b_in   [2048,1024]
  gemm_bt<64,64,16,4,4><<<dim3(HDIM/64, TB/64),256,0,stream>>>(
      inp_all, HDIM, W_in, HDIM, nullptr, gammaB, HDIM, b_in, nullptr,
      TB, HDIM, HDIM, 0);

  // attention scores/softmax/ctx
  attn_kernel<<<TB,256,0,stream>>>(gammaB, contexts, ctxB);

  // out = tanh(ctx @ Wout[:, :H]^T + inp @ Wout[:, H:]^T + b_out) -> d_out[0 .. 2048*1024)
  gemm_bt<64,64,16,4,4><<<dim3(HDIM/64, TB/64),256,0,stream>>>(
      ctxB, HDIM, W_out, 2*HDIM, nullptr, out, HDIM, nullptr, nullptr,
      TB, HDIM, HDIM, 0);
  gemm_bt<64,64,16,4,4><<<dim3(HDIM/64, TB/64),256,0,stream>>>(
      inp_all, HDIM, W_out + HDIM, 2*HDIM, out, out, HDIM, b_out, nullptr,
      TB, HDIM, HDIM, 1);

  // hT, cT
  copy_state_kernel<<<512,256,0,stream>>>(state, out + (size_t)TB*HDIM);
}

// Round 2
// 3124.263 us; speedup vs baseline: 7.6006x; 7.6006x over previous
//
#include <hip/hip_runtime.h>
#include <hip/hip_bf16.h>

#define HDIM 1024
#define BDIM 32
#define TDIM 64
#define SDIM 64
#define NL   2

typedef __attribute__((ext_vector_type(8))) short short8;
typedef __attribute__((ext_vector_type(4))) float f32x4;
typedef unsigned short ushort;
typedef unsigned int uint;

__device__ __forceinline__ float sigm(float x){ return 1.f/(1.f+expf(-x)); }
__device__ __forceinline__ ushort f2bf(float x){
  uint u = __float_as_uint(x);
  u = (u + 0x7FFF + ((u>>16)&1)) >> 16;   // RNE
  return (ushort)u;
}

// ---------------- init: fp32 state copy + bf16 h seeds ----------------
__global__ void init_state_kernel(const float* __restrict__ h0,
                                  const float* __restrict__ c0,
                                  float* __restrict__ st,     // h[2][32][1024], c[2][32][1024]
                                  ushort* __restrict__ hbuf){ // [4][32768]: l0p0,l0p1,l1p0,l1p1
  int i = blockIdx.x*256 + threadIdx.x;
  int n = NL*BDIM*HDIM;                   // 65536
  if(i < n){
    st[i] = h0[i];
    st[n+i] = c0[i];
    int l = i >> 15, r = i & 32767;       // layer, idx
    hbuf[(size_t)(l*2)*32768 + r] = f2bf(h0[i]);  // parity 0
  }
}

// ---------------- fp32 -> bf16 cast (vector x4) ----------------
__global__ void cast_kernel(const float* __restrict__ src, ushort* __restrict__ dst, int n4){
  int i = blockIdx.x*256 + threadIdx.x;
  if(i < n4){
    float4 v = ((const float4*)src)[i];
    ushort4 o; o.x=f2bf(v.x); o.y=f2bf(v.y); o.z=f2bf(v.z); o.w=f2bf(v.w);
    ((ushort4*)dst)[i] = o;
  }
}

// ---------------- combined biases ----------------
__global__ void bias_kernel(const float* __restrict__ b_ih, const float* __restrict__ b_hh,
                            float* __restrict__ bias0, float* __restrict__ bias1){
  int i = blockIdx.x*256 + threadIdx.x;   // 0..4095
  bias0[i] = b_ih[i] + b_hh[i];
  bias1[i] = b_ih[4096+i] + b_hh[4096+i];
}

// ---------------- embedding gather + bf16 cast ----------------
__global__ void embed_kernel(const int* __restrict__ tokens,
                             const float* __restrict__ emb,
                             ushort* __restrict__ Xb){
  int tb = blockIdx.x;
  int tok = tokens[tb];
  const float4* src = (const float4*)(emb + (size_t)tok*HDIM);
  ushort4* dst = (ushort4*)(Xb + (size_t)tb*HDIM);
  float4 v = src[threadIdx.x];
  ushort4 o; o.x=f2bf(v.x); o.y=f2bf(v.y); o.z=f2bf(v.z); o.w=f2bf(v.w);
  dst[threadIdx.x] = o;
}

// ---------------- big MFMA GEMM: C = act(A@B^T + bias) ----------------
// A: [M,K] bf16 (split at KSPLIT between A0,A1, same lda); B: [N,K] bf16; C fp32 [M,N]
// grid: (N/64, M/64), block 256 (4 waves; wave w -> 32x32 subtile)
__global__ __launch_bounds__(256) void gemm_mfma_bt(
    const ushort* __restrict__ A0, const ushort* __restrict__ A1, int lda, int KSPLIT,
    const ushort* __restrict__ B, int ldb,
    const float* __restrict__ bias,
    float* __restrict__ C, int ldc, int K, int act){
  __shared__ ushort As[64][40];
  __shared__ ushort Bs[64][40];
  const int bm = blockIdx.y*64, bn = blockIdx.x*64;
  const int tid = threadIdx.x, w = tid>>6, lane = tid&63;
  const int quad = lane>>4, l16 = lane&15;
  const int mh = (w>>1)*32, nh = (w&1)*32;
  const int arow = tid>>2, aseg = (tid&3)*8;
  f32x4 acc[2][2];
  #pragma unroll
  for(int i=0;i<2;i++)
    #pragma unroll
    for(int j=0;j<2;j++) acc[i][j] = (f32x4){0.f,0.f,0.f,0.f};

  for(int k0=0;k0<K;k0+=32){
    int gk = k0 + aseg;
    const ushort* ap = (gk < KSPLIT) ? (A0 + (size_t)(bm+arow)*lda + gk)
                                     : (A1 + (size_t)(bm+arow)*lda + (gk - KSPLIT));
    *(float4*)&As[arow][aseg] = *(const float4*)ap;
    *(float4*)&Bs[arow][aseg] = *(const float4*)(B + (size_t)(bn+arow)*ldb + k0 + aseg);
    __syncthreads();
    short8 a0 = *(const short8*)&As[mh + l16][quad*8];
    short8 a1 = *(const short8*)&As[mh + 16 + l16][quad*8];
    short8 b0 = *(const short8*)&Bs[nh + l16][quad*8];
    short8 b1 = *(const short8*)&Bs[nh + 16 + l16][quad*8];
    acc[0][0] = __builtin_amdgcn_mfma_f32_16x16x32_bf16(a0, b0, acc[0][0], 0,0,0);
    acc[0][1] = __builtin_amdgcn_mfma_f32_16x16x32_bf16(a0, b1, acc[0][1], 0,0,0);
    acc[1][0] = __builtin_amdgcn_mfma_f32_16x16x32_bf16(a1, b0, acc[1][0], 0,0,0);
    acc[1][1] = __builtin_amdgcn_mfma_f32_16x16x32_bf16(a1, b1, acc[1][1], 0,0,0);
    __syncthreads();
  }
  #pragma unroll
  for(int mi=0;mi<2;mi++){
    #pragma unroll
    for(int r=0;r<4;r++){
      int row = bm + mh + mi*16 + quad*4 + r;
      #pragma unroll
      for(int ni=0;ni<2;ni++){
        int col = bn + nh + ni*16 + l16;
        float v = acc[mi][ni][r];
        if(bias) v += bias[col];
        if(act) v = tanhf(v);
        C[(size_t)row*ldc + col] = v;
      }
    }
  }
}

// ---------------- fused LSTM step: gates = A@W^T (+add/+bias) -> cell ----------------
// A = h (bf16, [32][1024] per half), W rows gate-major [4096][1024] per half.
// grid: 64 blocks x 256 thr. Block nb handles per-gate cols jb=nb*16..+15.
// Wave w computes gate w's 32x16 tile; cell applied via LDS.
template<int KK>
__global__ __launch_bounds__(256) void lstm_step(
    const ushort* __restrict__ hA0, const ushort* __restrict__ hA1,
    const ushort* __restrict__ W0, const ushort* __restrict__ W1,
    const float* __restrict__ add4096,   // G0 row base [32][4096] or null
    const float* __restrict__ bias4096,  // combined bias or null
    float* __restrict__ cstate, float* __restrict__ hstate,
    ushort* __restrict__ hb_out, ushort* __restrict__ inp_bf_out){
  const int tid = threadIdx.x, w = tid>>6, lane = tid&63;
  const int quad = lane>>4, l16 = lane&15;
  const int jb = blockIdx.x*16;
  f32x4 acc0 = {0.f,0.f,0.f,0.f}, acc1 = {0.f,0.f,0.f,0.f};
  const int n = w*1024 + jb + l16;       // weight row (gate-major)
  #pragma unroll 4
  for(int kc=0; kc<KK/32; kc++){
    int k = kc*32 + quad*8;
    const ushort *ap, *wp;
    if(KK==2048 && k>=1024){
      ap = hA1 + (k-1024);
      wp = W1 + (size_t)n*1024 + (k-1024);
    } else {
      ap = hA0 + k;
      wp = W0 + (size_t)n*1024 + k;
    }
    short8 a0 = *(const short8*)(ap + (size_t)l16*1024);
    short8 a1 = *(const short8*)(ap + (size_t)(l16+16)*1024);
    short8 b  = *(const short8*)wp;
    acc0 = __builtin_amdgcn_mfma_f32_16x16x32_bf16(a0, b, acc0, 0,0,0);
    acc1 = __builtin_amdgcn_mfma_f32_16x16x32_bf16(a1, b, acc1, 0,0,0);
  }
  __shared__ float gt[4][32][17];
  #pragma unroll
  for(int r=0;r<4;r++){
    gt[w][quad*4+r][l16]      = acc0[r];
    gt[w][16+quad*4+r][l16]   = acc1[r];
  }
  __syncthreads();
  #pragma unroll
  for(int e=tid; e<512; e+=256){
    int b = e>>4, jj = e&15, j = jb + jj;
    float gi = gt[0][b][jj], gf = gt[1][b][jj], gg = gt[2][b][jj], go = gt[3][b][jj];
    if(add4096){
      const float* ar = add4096 + (size_t)b*4096;
      gi += ar[j]; gf += ar[1024+j]; gg += ar[2048+j]; go += ar[3072+j];
    }
    if(bias4096){
      gi += bias4096[j]; gf += bias4096[1024+j]; gg += bias4096[2048+j]; go += bias4096[3072+j];
    }
    int idx = b*HDIM + j;
    float c = cstate[idx];
    float c1 = sigm(gf)*c + sigm(gi)*tanhf(gg);
    float h1 = sigm(go)*tanhf(c1);
    cstate[idx] = c1;
    hstate[idx] = h1;
    ushort hb = f2bf(h1);
    hb_out[idx] = hb;
    if(inp_bf_out) inp_bf_out[idx] = hb;
  }
}

// ---------------- attention: scores -> softmax -> ctx (bf16 out) ----------------
__global__ void attn_kernel(const float* __restrict__ gamma,    // [T*B, H] fp32
                            const float* __restrict__ contexts, // [B, S, H] fp32
                            ushort* __restrict__ ctxout){       // [T*B, H] bf16
  int tb = blockIdx.x;
  int b = tb & (BDIM-1);
  const float* g  = gamma + (size_t)tb*HDIM;
  const float* cb = contexts + (size_t)b*SDIM*HDIM;
  __shared__ float sc[SDIM];
  __shared__ float wexp[SDIM];
  __shared__ float red[256];
  int tid = threadIdx.x;
  int s = tid >> 2, q = tid & 3;
  float p = 0.f;
  const float* row = cb + (size_t)s*HDIM;
  for(int k=q*256;k<q*256+256;k++) p += g[k]*row[k];
  red[tid] = p;
  __syncthreads();
  if(q==0) sc[s] = red[tid]+red[tid+1]+red[tid+2]+red[tid+3];
  __syncthreads();
  float mx = -1e30f;
  for(int s2=0;s2<SDIM;s2++) mx = fmaxf(mx, sc[s2]);
  if(tid < SDIM) wexp[tid] = expf(sc[tid]-mx);
  __syncthreads();
  float sum = 0.f;
  for(int s2=0;s2<SDIM;s2++) sum += wexp[s2];
  float inv = 1.f/sum;
  for(int hh=tid; hh<HDIM; hh+=256){
    float a = 0.f;
    for(int s2=0;s2<SDIM;s2++) a += wexp[s2]*cb[(size_t)s2*HDIM + hh];
    ctxout[(size_t)tb*HDIM + hh] = f2bf(a*inv);
  }
}

// ---------------- final state copy ----------------
__global__ void copy_state_kernel(const float* __restrict__ st, float* __restrict__ dst){
  int i = blockIdx.x*256 + threadIdx.x;
  if(i < 2*NL*BDIM*HDIM) dst[i] = st[i];
}

extern "C" void kernel_launch(void* const* d_in, const int* in_sizes, int n_in,
                              void* d_out, int out_size, void* d_ws, size_t ws_size,
                              hipStream_t stream){
  const int*   tokens   = (const int*)  d_in[0];
  const float* h0       = (const float*)d_in[1];
  const float* c0       = (const float*)d_in[2];
  const float* contexts = (const float*)d_in[3];
  const float* emb      = (const float*)d_in[4];
  const float* W_ih     = (const float*)d_in[5];   // [2,4H,H]
  const float* W_hh     = (const float*)d_in[6];
  const float* b_ih     = (const float*)d_in[7];   // [2,4H]
  const float* b_hh     = (const float*)d_in[8];
  const float* W_in     = (const float*)d_in[9];   // [H,H]
  const float* b_in     = (const float*)d_in[10];
  const float* W_out    = (const float*)d_in[11];  // [H,2H]
  const float* b_out    = (const float*)d_in[12];

  float* out = (float*)d_out;
  const int TB = TDIM*BDIM;                       // 2048

  // ---- workspace layout ----
  char* wp = (char*)d_ws;
  float* state   = (float*)wp;  wp += (size_t)2*NL*BDIM*HDIM*4;     // 131072 f
  float* G0      = (float*)wp;  wp += (size_t)TB*4*HDIM*4;          // 8.4M f (gammaB overlays)
  float* bias0c  = (float*)wp;  wp += 4096*4;
  float* bias1c  = (float*)wp;  wp += 4096*4;
  ushort* X_bf   = (ushort*)wp; wp += (size_t)TB*HDIM*2;            // ctx_bf overlays after G0 GEMM
  ushort* Wih0b  = (ushort*)wp; wp += (size_t)4*HDIM*HDIM*2;
  ushort* Whh0b  = (ushort*)wp; wp += (size_t)4*HDIM*HDIM*2;
  ushort* Wih1b  = (ushort*)wp; wp += (size_t)4*HDIM*HDIM*2;
  ushort* Whh1b  = (ushort*)wp; wp += (size_t)4*HDIM*HDIM*2;
  ushort* Winb   = (ushort*)wp; wp += (size_t)HDIM*HDIM*2;
  ushort* Woutb  = (ushort*)wp; wp += (size_t)HDIM*2*HDIM*2;
  ushort* inp_bf = (ushort*)wp; wp += (size_t)TB*HDIM*2;
  ushort* hbuf   = (ushort*)wp; wp += (size_t)4*BDIM*HDIM*2;        // [l0p0,l0p1,l1p0,l1p1]
  float* gammaB  = G0;                                              // overlay (G0 dead after scan)
  ushort* ctx_bf = X_bf;                                            // overlay (X dead after G0 GEMM)

  float* h0s = state;
  float* h1s = state + BDIM*HDIM;
  float* c0s = state + 2*BDIM*HDIM;
  float* c1s = state + 3*BDIM*HDIM;
  ushort* hb0[2] = { hbuf,                hbuf +   BDIM*HDIM };
  ushort* hb1[2] = { hbuf + 2*BDIM*HDIM,  hbuf + 3*BDIM*HDIM };

  // ---- prep: state init, weight casts, biases, embedding ----
  init_state_kernel<<<256,256,0,stream>>>(h0, c0, state, hbuf);
  cast_kernel<<<4096,256,0,stream>>>(W_ih,                       Wih0b, 4*HDIM*HDIM/4);
  cast_kernel<<<4096,256,0,stream>>>(W_hh,                       Whh0b, 4*HDIM*HDIM/4);
  cast_kernel<<<4096,256,0,stream>>>(W_ih + (size_t)4*HDIM*HDIM, Wih1b, 4*HDIM*HDIM/4);
  cast_kernel<<<4096,256,0,stream>>>(W_hh + (size_t)4*HDIM*HDIM, Whh1b, 4*HDIM*HDIM/4);
  cast_kernel<<<1024,256,0,stream>>>(W_in,  Winb,  HDIM*HDIM/4);
  cast_kernel<<<2048,256,0,stream>>>(W_out, Woutb, HDIM*2*HDIM/4);
  bias_kernel<<<16,256,0,stream>>>(b_ih, b_hh, bias0c, bias1c);
  embed_kernel<<<TB,256,0,stream>>>(tokens, emb, X_bf);

  // ---- G0 = X @ Wih0^T + (b_ih0 + b_hh0)   [2048,4096] fp32 ----
  gemm_mfma_bt<<<dim3(4*HDIM/64, TB/64),256,0,stream>>>(
      X_bf, X_bf, HDIM, HDIM, Wih0b, HDIM, bias0c, G0, 4*HDIM, HDIM, 0);

  // ---- recurrence: 2 fused kernels per step ----
  for(int t=0;t<TDIM;t++){
    int p = t & 1, q = p ^ 1;
    lstm_step<1024><<<64,256,0,stream>>>(
        hb0[p], hb0[p], Whh0b, Whh0b,
        G0 + (size_t)t*BDIM*4*HDIM, nullptr,
        c0s, h0s, hb0[q], nullptr);
    lstm_step<2048><<<64,256,0,stream>>>(
        hb0[q], hb1[p], Wih1b, Whh1b,
        nullptr, bias1c,
        c1s, h1s, hb1[q], inp_bf + (size_t)t*BDIM*HDIM);
  }

  // ---- gamma = inp @ W_in^T + b_in  [2048,1024] fp32 (overlays G0) ----
  gemm_mfma_bt<<<dim3(HDIM/64, TB/64),256,0,stream>>>(
      inp_bf, inp_bf, HDIM, HDIM, Winb, HDIM, b_in, gammaB, HDIM, HDIM, 0);

  // ---- attention ----
  attn_kernel<<<TB,256,0,stream>>>(gammaB, contexts, ctx_bf);

  // ---- out = tanh([ctx|inp] @ W_out^T + b_out) -> d_out ----
  gemm_mfma_bt<<<dim3(HDIM/64, TB/64),256,0,stream>>>(
      ctx_bf, inp_bf, HDIM, HDIM, Woutb, 2*HDIM, b_out, out, HDIM, 2*HDIM, 1);

  // ---- hT, cT ----
  copy_state_kernel<<<512,256,0,stream>>>(state, out + (size_t)TB*HDIM);
}

// Round 3
// 2012.966 us; speedup vs baseline: 11.7967x; 1.5521x over previous
//
#include <hip/hip_runtime.h>
#include <hip/hip_bf16.h>

#define HDIM 1024
#define BDIM 32
#define TDIM 64
#define SDIM 64
#define NL   2
#define NBLK 256

typedef __attribute__((ext_vector_type(8))) short short8;
typedef __attribute__((ext_vector_type(4))) float f32x4;
typedef unsigned short ushort;
typedef unsigned int uint;

__device__ __forceinline__ float sigm(float x){ return 1.f/(1.f+expf(-x)); }
__device__ __forceinline__ ushort f2bf(float x){
  uint u = __float_as_uint(x);
  u = (u + 0x7FFF + ((u>>16)&1)) >> 16;   // RNE
  return (ushort)u;
}
#define MFMA16(a,b,c) __builtin_amdgcn_mfma_f32_16x16x32_bf16((a),(b),(c),0,0,0)

// ---------------- init: bf16 h seeds (parity 0 for both layers) ----------------
__global__ void init_state_kernel(const float* __restrict__ h0,
                                  ushort* __restrict__ hbuf){ // [4][32768]: l0p0,l0p1,l1p0,l1p1
  int i = blockIdx.x*256 + threadIdx.x;       // 0..65535
  int l = i >> 15, r = i & 32767;
  hbuf[(size_t)(l*2)*32768 + r] = f2bf(h0[i]);
}

__global__ void bar_init_kernel(int* bar){ *bar = 0; }

// ---------------- fp32 -> bf16 cast (vector x4) ----------------
__global__ void cast_kernel(const float* __restrict__ src, ushort* __restrict__ dst, int n4){
  int i = blockIdx.x*256 + threadIdx.x;
  if(i < n4){
    float4 v = ((const float4*)src)[i];
    ushort4 o; o.x=f2bf(v.x); o.y=f2bf(v.y); o.z=f2bf(v.z); o.w=f2bf(v.w);
    ((ushort4*)dst)[i] = o;
  }
}

// ---------------- contexts transpose: [32][64][1024] f32 -> [32][1024][64] bf16 ----
__global__ void transpose_ctx_kernel(const float* __restrict__ ctx, ushort* __restrict__ ctxT){
  int b = blockIdx.y;
  int n = blockIdx.x*64 + (threadIdx.x & 63);
  int s0 = (threadIdx.x >> 6) * 16;
  for(int s=s0; s<s0+16; s++){
    float v = ctx[((size_t)b*SDIM + s)*HDIM + n];
    ctxT[((size_t)b*HDIM + n)*SDIM + s] = f2bf(v);
  }
}

// ---------------- combined biases ----------------
__global__ void bias_kernel(const float* __restrict__ b_ih, const float* __restrict__ b_hh,
                            float* __restrict__ bias0, float* __restrict__ bias1){
  int i = blockIdx.x*256 + threadIdx.x;   // 0..4095
  bias0[i] = b_ih[i] + b_hh[i];
  bias1[i] = b_ih[4096+i] + b_hh[4096+i];
}

// ---------------- embedding gather + bf16 cast ----------------
__global__ void embed_kernel(const int* __restrict__ tokens,
                             const float* __restrict__ emb,
                             ushort* __restrict__ Xb){
  int tb = blockIdx.x;
  int tok = tokens[tb];
  const float4* src = (const float4*)(emb + (size_t)tok*HDIM);
  ushort4* dst = (ushort4*)(Xb + (size_t)tb*HDIM);
  float4 v = src[threadIdx.x];
  ushort4 o; o.x=f2bf(v.x); o.y=f2bf(v.y); o.z=f2bf(v.z); o.w=f2bf(v.w);
  dst[threadIdx.x] = o;
}

// ---------------- big MFMA GEMM: C = act(A@B^T + bias) ----------------
// act: 0 = fp32 store, 1 = tanh fp32 store, 2 = bf16 store
__global__ __launch_bounds__(256) void gemm_mfma_bt(
    const ushort* __restrict__ A0, const ushort* __restrict__ A1, int lda, int KSPLIT,
    const ushort* __restrict__ B, int ldb,
    const float* __restrict__ bias,
    float* __restrict__ C, int ldc, int K, int act){
  __shared__ ushort As[64][40];
  __shared__ ushort Bs[64][40];
  const int bm = blockIdx.y*64, bn = blockIdx.x*64;
  const int tid = threadIdx.x, w = tid>>6, lane = tid&63;
  const int quad = lane>>4, l16 = lane&15;
  const int mh = (w>>1)*32, nh = (w&1)*32;
  const int arow = tid>>2, aseg = (tid&3)*8;
  f32x4 acc[2][2];
  #pragma unroll
  for(int i=0;i<2;i++)
    #pragma unroll
    for(int j=0;j<2;j++) acc[i][j] = (f32x4){0.f,0.f,0.f,0.f};

  for(int k0=0;k0<K;k0+=32){
    int gk = k0 + aseg;
    const ushort* ap = (gk < KSPLIT) ? (A0 + (size_t)(bm+arow)*lda + gk)
                                     : (A1 + (size_t)(bm+arow)*lda + (gk - KSPLIT));
    *(float4*)&As[arow][aseg] = *(const float4*)ap;
    *(float4*)&Bs[arow][aseg] = *(const float4*)(B + (size_t)(bn+arow)*ldb + k0 + aseg);
    __syncthreads();
    short8 a0 = *(const short8*)&As[mh + l16][quad*8];
    short8 a1 = *(const short8*)&As[mh + 16 + l16][quad*8];
    short8 b0 = *(const short8*)&Bs[nh + l16][quad*8];
    short8 b1 = *(const short8*)&Bs[nh + 16 + l16][quad*8];
    acc[0][0] = MFMA16(a0, b0, acc[0][0]);
    acc[0][1] = MFMA16(a0, b1, acc[0][1]);
    acc[1][0] = MFMA16(a1, b0, acc[1][0]);
    acc[1][1] = MFMA16(a1, b1, acc[1][1]);
    __syncthreads();
  }
  #pragma unroll
  for(int mi=0;mi<2;mi++){
    #pragma unroll
    for(int r=0;r<4;r++){
      int row = bm + mh + mi*16 + quad*4 + r;
      #pragma unroll
      for(int ni=0;ni<2;ni++){
        int col = bn + nh + ni*16 + l16;
        float v = acc[mi][ni][r];
        if(bias) v += bias[col];
        if(act==1) v = tanhf(v);
        if(act==2) ((ushort*)C)[(size_t)row*ldc + col] = f2bf(v);
        else       C[(size_t)row*ldc + col] = v;
      }
    }
  }
}

// ---------------- persistent LSTM scan ----------------
__global__ void lstm_persistent(
    const ushort* __restrict__ Whh0b,   // [4096][1024] bf16
    const ushort* __restrict__ Wih1b,   // [4096][1024]
    const ushort* __restrict__ Whh1b,   // [4096][1024]
    const float*  __restrict__ G0,      // [T*32][4096] fp32 (bias0 folded)
    const float*  __restrict__ bias1c,  // [4096]
    const float*  __restrict__ c0in,    // [2][32][1024]
    ushort* __restrict__ hbuf,          // [4][32][1024]: l0p0,l0p1,l1p0,l1p1
    ushort* __restrict__ inp_bf,        // [T*32][1024]
    float*  __restrict__ outstate,      // h[2][32][1024] then c[2][32][1024]
    int* __restrict__ bar){
  extern __shared__ char smem[];
  ushort (*W0s)[1032] = (ushort(*)[1032])smem;                    // 33024 B
  ushort (*W1s)[2056] = (ushort(*)[2056])(smem + 33024);          // 65792 B
  float (*gred)[32][17] = (float(*)[32][17])(smem + 98816);       // 8704 B
  float (*cloc)[32][4]  = (float(*)[32][4]) (smem + 107520);      // 1024 B

  const int tid = threadIdx.x, w = tid>>6, lane = tid&63;
  const int quad = lane>>4, l16 = lane&15;
  const int blk = blockIdx.x;
  const int j0 = blk*4;

  // ---- load weight slices into LDS (held for all 64 steps) ----
  {
    int r = tid>>4, seg = tid&15;                       // 16 rows x 16 segments
    int wr = (r>>2)*1024 + j0 + (r&3);                  // gate-major weight row
    const ushort* s0 = Whh0b + (size_t)wr*1024 + seg*64;
    const ushort* s1 = Wih1b + (size_t)wr*1024 + seg*64;
    const ushort* s2 = Whh1b + (size_t)wr*1024 + seg*64;
    #pragma unroll
    for(int u=0; u<64; u+=8){
      *(short8*)&W0s[r][seg*64+u]       = *(const short8*)(s0+u);
      *(short8*)&W1s[r][seg*64+u]       = *(const short8*)(s1+u);
      *(short8*)&W1s[r][1024+seg*64+u]  = *(const short8*)(s2+u);
    }
  }
  if(tid < 128){
    int b = tid>>2, jj = tid&3;
    cloc[0][b][jj] = c0in[b*1024 + j0 + jj];
    cloc[1][b][jj] = c0in[32768 + b*1024 + j0 + jj];
  }
  __syncthreads();

  ushort* hb0[2] = { hbuf,            hbuf + 32768 };
  ushort* hb1[2] = { hbuf + 2*32768,  hbuf + 3*32768 };

  int barcnt = 0;
  for(int t=0; t<TDIM; t++){
    int p = t&1, q = p^1;
    // ================= phase 0: layer 0 =================
    {
      const ushort* hsrc = hb0[p];
      f32x4 acc0 = {0,0,0,0}, acc1 = {0,0,0,0};
      int kbase = w*256;
      #pragma unroll
      for(int kc=0;kc<8;kc++){
        int k = kbase + kc*32 + quad*8;
        short8 bfrag = *(const short8*)&W0s[l16][k];
        short8 af0 = *(const short8*)(hsrc + (size_t)l16*1024 + k);
        short8 af1 = *(const short8*)(hsrc + (size_t)(l16+16)*1024 + k);
        acc0 = MFMA16(af0, bfrag, acc0);
        acc1 = MFMA16(af1, bfrag, acc1);
      }
      #pragma unroll
      for(int r=0;r<4;r++){
        gred[w][quad*4+r][l16]    = acc0[r];
        gred[w][16+quad*4+r][l16] = acc1[r];
      }
      __syncthreads();
      if(tid < 64){
        int b = tid>>1, j2 = (tid&1)*2;
        const float* g0r = G0 + (size_t)(t*32+b)*4096 + j0;
        ushort hv[2];
        #pragma unroll
        for(int u=0;u<2;u++){
          int jj = j2+u;
          float gi=g0r[jj], gf=g0r[1024+jj], gg=g0r[2048+jj], go=g0r[3072+jj];
          #pragma unroll
          for(int ww=0;ww<4;ww++){
            gi += gred[ww][b][jj];    gf += gred[ww][b][4+jj];
            gg += gred[ww][b][8+jj];  go += gred[ww][b][12+jj];
          }
          float c = cloc[0][b][jj];
          float c1 = sigm(gf)*c + sigm(gi)*tanhf(gg);
          float h1 = sigm(go)*tanhf(c1);
          cloc[0][b][jj] = c1;
          hv[u] = f2bf(h1);
          if(t==TDIM-1){
            outstate[b*1024 + j0 + jj] = h1;          // hT layer0
            outstate[65536 + b*1024 + j0 + jj] = c1;  // cT layer0
          }
        }
        uint pk = (uint)hv[0] | ((uint)hv[1] << 16);
        __hip_atomic_store((uint*)(hb0[q] + b*1024 + j0 + j2), pk,
                           __ATOMIC_RELAXED, __HIP_MEMORY_SCOPE_AGENT);
      }
    }
    // ================= device barrier =================
    barcnt += NBLK;
    __syncthreads();                       // drains this block's stores
    if(tid==0){
      __threadfence();
      __hip_atomic_fetch_add(bar, 1, __ATOMIC_RELEASE, __HIP_MEMORY_SCOPE_AGENT);
      while(__hip_atomic_load(bar, __ATOMIC_RELAXED, __HIP_MEMORY_SCOPE_AGENT) < barcnt){
        __builtin_amdgcn_s_sleep(8);
      }
      __threadfence();                     // invalidate caches before reading peers' h
    }
    __syncthreads();
    // ================= phase 1: layer 1 (K=2048: [h0'; h1]) =================
    {
      f32x4 acc0 = {0,0,0,0}, acc1 = {0,0,0,0};
      int kbase = w*512;
      #pragma unroll
      for(int kc=0;kc<16;kc++){
        int k = kbase + kc*32 + quad*8;
        short8 bfrag = *(const short8*)&W1s[l16][k];
        const ushort* hsrc = (k < 1024) ? (hb0[q] + k) : (hb1[p] + (k-1024));
        short8 af0 = *(const short8*)(hsrc + (size_t)l16*1024);
        short8 af1 = *(const short8*)(hsrc + (size_t)(l16+16)*1024);
        acc0 = MFMA16(af0, bfrag, acc0);
        acc1 = MFMA16(af1, bfrag, acc1);
      }
      #pragma unroll
      for(int r=0;r<4;r++){
        gred[w][quad*4+r][l16]    = acc0[r];
        gred[w][16+quad*4+r][l16] = acc1[r];
      }
      __syncthreads();
      if(tid < 64){
        int b = tid>>1, j2 = (tid&1)*2;
        ushort hv[2];
        #pragma unroll
        for(int u=0;u<2;u++){
          int jj = j2+u;
          float gi=bias1c[j0+jj], gf=bias1c[1024+j0+jj],
                gg=bias1c[2048+j0+jj], go=bias1c[3072+j0+jj];
          #pragma unroll
          for(int ww=0;ww<4;ww++){
            gi += gred[ww][b][jj];    gf += gred[ww][b][4+jj];
            gg += gred[ww][b][8+jj];  go += gred[ww][b][12+jj];
          }
          float c = cloc[1][b][jj];
          float c1 = sigm(gf)*c + sigm(gi)*tanhf(gg);
          float h1 = sigm(go)*tanhf(c1);
          cloc[1][b][jj] = c1;
          hv[u] = f2bf(h1);
          inp_bf[(size_t)(t*32+b)*1024 + j0 + jj] = hv[u];
          if(t==TDIM-1){
            outstate[32768 + b*1024 + j0 + jj] = h1;          // hT layer1
            outstate[65536 + 32768 + b*1024 + j0 + jj] = c1;  // cT layer1
          }
        }
        uint pk = (uint)hv[0] | ((uint)hv[1] << 16);
        __hip_atomic_store((uint*)(hb1[q] + b*1024 + j0 + j2), pk,
                           __ATOMIC_RELAXED, __HIP_MEMORY_SCOPE_AGENT);
      }
      __syncthreads();                    // gred reused by next step's phase0
    }
  }
}

// ---------------- MFMA attention: block = (t-chunk of 16, b) ----------------
__global__ __launch_bounds__(256) void attn_mfma(
    const ushort* __restrict__ gamma_bf, // [2048][1024] rows t*32+b
    const ushort* __restrict__ ctxb,     // [32][64][1024] bf16
    const ushort* __restrict__ ctxT,     // [32][1024][64] bf16
    ushort* __restrict__ ctx_out){       // [2048][1024] bf16
  const int b = blockIdx.y, t0 = blockIdx.x*16;
  const int tid = threadIdx.x, w = tid>>6, lane = tid&63;
  const int quad = lane>>4, l16 = lane&15;
  __shared__ float S[16][68];
  __shared__ ushort Pb[16][72];
  {
    f32x4 acc = {0,0,0,0};
    const ushort* arow = gamma_bf + ((size_t)(t0+l16)*32 + b)*1024;
    const ushort* brow = ctxb + ((size_t)b*SDIM + w*16 + l16)*1024;
    #pragma unroll 8
    for(int kc=0;kc<32;kc++){
      short8 af = *(const short8*)(arow + kc*32 + quad*8);
      short8 bf = *(const short8*)(brow + kc*32 + quad*8);
      acc = MFMA16(af, bf, acc);
    }
    #pragma unroll
    for(int r=0;r<4;r++) S[quad*4+r][w*16+l16] = acc[r];
  }
  __syncthreads();
  if(tid < 16){
    float mx = -1e30f;
    for(int s=0;s<SDIM;s++) mx = fmaxf(mx, S[tid][s]);
    float sum = 0.f;
    for(int s=0;s<SDIM;s++) sum += expf(S[tid][s]-mx);
    float inv = 1.f/sum;
    for(int s=0;s<SDIM;s++) Pb[tid][s] = f2bf(expf(S[tid][s]-mx)*inv);
  }
  __syncthreads();
  const ushort* bbase = ctxT + ((size_t)b*HDIM + w*256)*SDIM;
  for(int nt=0; nt<16; nt++){
    f32x4 acc = {0,0,0,0};
    #pragma unroll
    for(int kc=0;kc<2;kc++){
      short8 af = *(const short8*)&Pb[l16][kc*32 + quad*8];
      short8 bf = *(const short8*)(bbase + (size_t)(nt*16+l16)*SDIM + kc*32 + quad*8);
      acc = MFMA16(af, bf, acc);
    }
    int n = w*256 + nt*16 + l16;
    #pragma unroll
    for(int r=0;r<4;r++){
      int t = t0 + quad*4 + r;
      ctx_out[((size_t)t*32 + b)*1024 + n] = f2bf(acc[r]);
    }
  }
}

extern "C" void kernel_launch(void* const* d_in, const int* in_sizes, int n_in,
                              void* d_out, int out_size, void* d_ws, size_t ws_size,
                              hipStream_t stream){
  const int*   tokens   = (const int*)  d_in[0];
  const float* h0       = (const float*)d_in[1];
  const float* c0       = (const float*)d_in[2];
  const float* contexts = (const float*)d_in[3];
  const float* emb      = (const float*)d_in[4];
  const float* W_ih     = (const float*)d_in[5];   // [2,4H,H]
  const float* W_hh     = (const float*)d_in[6];
  const float* b_ih     = (const float*)d_in[7];   // [2,4H]
  const float* b_hh     = (const float*)d_in[8];
  const float* W_in     = (const float*)d_in[9];   // [H,H]
  const float* b_in     = (const float*)d_in[10];
  const float* W_out    = (const float*)d_in[11];  // [H,2H]
  const float* b_out    = (const float*)d_in[12];

  float* out = (float*)d_out;
  const int TB = TDIM*BDIM;                        // 2048

  // ---- workspace layout ----
  char* wp = (char*)d_ws;
  float* G0      = (float*)wp;  wp += (size_t)TB*4*HDIM*4;          // 33.5 MB
  float* bias0c  = (float*)wp;  wp += 4096*4;
  float* bias1c  = (float*)wp;  wp += 4096*4;
  int*   bar     = (int*)wp;    wp += 256;
  ushort* X_bf   = (ushort*)wp; wp += (size_t)TB*HDIM*2;
  ushort* Wih0b  = (ushort*)wp; wp += (size_t)4*HDIM*HDIM*2;
  ushort* Whh0b  = (ushort*)wp; wp += (size_t)4*HDIM*HDIM*2;
  ushort* Wih1b  = (ushort*)wp; wp += (size_t)4*HDIM*HDIM*2;
  ushort* Whh1b  = (ushort*)wp; wp += (size_t)4*HDIM*HDIM*2;
  ushort* Winb   = (ushort*)wp; wp += (size_t)HDIM*HDIM*2;
  ushort* Woutb  = (ushort*)wp; wp += (size_t)HDIM*2*HDIM*2;
  ushort* inp_bf = (ushort*)wp; wp += (size_t)TB*HDIM*2;
  ushort* hbuf   = (ushort*)wp; wp += (size_t)4*BDIM*HDIM*2;
  ushort* ctxb_bf= (ushort*)wp; wp += (size_t)BDIM*SDIM*HDIM*2;
  ushort* ctxT_bf= (ushort*)wp; wp += (size_t)BDIM*SDIM*HDIM*2;
  ushort* gammaB = (ushort*)G0;                                     // overlay
  ushort* ctx_bf = X_bf;                                            // overlay

  // ---- prep ----
  init_state_kernel<<<256,256,0,stream>>>(h0, hbuf);
  bar_init_kernel<<<1,1,0,stream>>>(bar);
  cast_kernel<<<4096,256,0,stream>>>(W_ih,                       Wih0b, 4*HDIM*HDIM/4);
  cast_kernel<<<4096,256,0,stream>>>(W_hh,                       Whh0b, 4*HDIM*HDIM/4);
  cast_kernel<<<4096,256,0,stream>>>(W_ih + (size_t)4*HDIM*HDIM, Wih1b, 4*HDIM*HDIM/4);
  cast_kernel<<<4096,256,0,stream>>>(W_hh + (size_t)4*HDIM*HDIM, Whh1b, 4*HDIM*HDIM/4);
  cast_kernel<<<1024,256,0,stream>>>(W_in,  Winb,  HDIM*HDIM/4);
  cast_kernel<<<2048,256,0,stream>>>(W_out, Woutb, HDIM*2*HDIM/4);
  cast_kernel<<<2048,256,0,stream>>>(contexts, ctxb_bf, BDIM*SDIM*HDIM/4);
  transpose_ctx_kernel<<<dim3(16,32),256,0,stream>>>(contexts, ctxT_bf);
  bias_kernel<<<16,256,0,stream>>>(b_ih, b_hh, bias0c, bias1c);
  embed_kernel<<<TB,256,0,stream>>>(tokens, emb, X_bf);

  // ---- G0 = X @ Wih0^T + (b_ih0+b_hh0)  [2048,4096] fp32 ----
  gemm_mfma_bt<<<dim3(4*HDIM/64, TB/64),256,0,stream>>>(
      X_bf, X_bf, HDIM, HDIM, Wih0b, HDIM, bias0c, G0, 4*HDIM, HDIM, 0);

  // ---- persistent LSTM scan (1 dispatch, 64 steps) ----
  lstm_persistent<<<NBLK,256,108544,stream>>>(
      Whh0b, Wih1b, Whh1b, G0, bias1c, c0,
      hbuf, inp_bf, out + (size_t)TB*HDIM, bar);

  // ---- gamma = inp @ W_in^T + b_in -> bf16 (overlays G0) ----
  gemm_mfma_bt<<<dim3(HDIM/64, TB/64),256,0,stream>>>(
      inp_bf, inp_bf, HDIM, HDIM, Winb, HDIM, b_in, (float*)gammaB, HDIM, HDIM, 2);

  // ---- attention (MFMA) ----
  attn_mfma<<<dim3(4,32),256,0,stream>>>(gammaB, ctxb_bf, ctxT_bf, ctx_bf);

  // ---- out = tanh([ctx|inp] @ W_out^T + b_out) -> d_out ----
  gemm_mfma_bt<<<dim3(HDIM/64, TB/64),256,0,stream>>>(
      ctx_bf, inp_bf, HDIM, HDIM, Woutb, 2*HDIM, b_out, out, HDIM, 2*HDIM, 1);
}

// Round 4
// 1864.725 us; speedup vs baseline: 12.7345x; 1.0795x over previous
//
#include <hip/hip_runtime.h>
#include <hip/hip_bf16.h>

#define HDIM 1024
#define BDIM 32
#define TDIM 64
#define SDIM 64
#define NL   2
#define NBLK 256

typedef __attribute__((ext_vector_type(8))) short short8;
typedef __attribute__((ext_vector_type(4))) float f32x4;
typedef unsigned short ushort;
typedef unsigned int uint;

__device__ __forceinline__ float sigm(float x){ return 1.f/(1.f+expf(-x)); }
__device__ __forceinline__ ushort f2bf(float x){
  uint u = __float_as_uint(x);
  u = (u + 0x7FFF + ((u>>16)&1)) >> 16;   // RNE
  return (ushort)u;
}
#define MFMA16(a,b,c) __builtin_amdgcn_mfma_f32_16x16x32_bf16((a),(b),(c),0,0,0)

// ---------------- init: bf16 h seeds (parity 0 for both layers) ----------------
__global__ void init_state_kernel(const float* __restrict__ h0,
                                  ushort* __restrict__ hbuf){ // [4][32768]: l0p0,l0p1,l1p0,l1p1
  int i = blockIdx.x*256 + threadIdx.x;       // 0..65535
  int l = i >> 15, r = i & 32767;
  hbuf[(size_t)(l*2)*32768 + r] = f2bf(h0[i]);
}

__global__ void bar_init_kernel(int* flags){ flags[threadIdx.x] = 0; }

// ---------------- fp32 -> bf16 cast (vector x4) ----------------
__global__ void cast_kernel(const float* __restrict__ src, ushort* __restrict__ dst, int n4){
  int i = blockIdx.x*256 + threadIdx.x;
  if(i < n4){
    float4 v = ((const float4*)src)[i];
    ushort4 o; o.x=f2bf(v.x); o.y=f2bf(v.y); o.z=f2bf(v.z); o.w=f2bf(v.w);
    ((ushort4*)dst)[i] = o;
  }
}

// ---------------- contexts transpose: [32][64][1024] f32 -> [32][1024][64] bf16 ----
__global__ void transpose_ctx_kernel(const float* __restrict__ ctx, ushort* __restrict__ ctxT){
  int b = blockIdx.y;
  int n = blockIdx.x*64 + (threadIdx.x & 63);
  int s0 = (threadIdx.x >> 6) * 16;
  for(int s=s0; s<s0+16; s++){
    float v = ctx[((size_t)b*SDIM + s)*HDIM + n];
    ctxT[((size_t)b*HDIM + n)*SDIM + s] = f2bf(v);
  }
}

// ---------------- combined biases ----------------
__global__ void bias_kernel(const float* __restrict__ b_ih, const float* __restrict__ b_hh,
                            float* __restrict__ bias0, float* __restrict__ bias1){
  int i = blockIdx.x*256 + threadIdx.x;   // 0..4095
  bias0[i] = b_ih[i] + b_hh[i];
  bias1[i] = b_ih[4096+i] + b_hh[4096+i];
}

// ---------------- embedding gather + bf16 cast ----------------
__global__ void embed_kernel(const int* __restrict__ tokens,
                             const float* __restrict__ emb,
                             ushort* __restrict__ Xb){
  int tb = blockIdx.x;
  int tok = tokens[tb];
  const float4* src = (const float4*)(emb + (size_t)tok*HDIM);
  ushort4* dst = (ushort4*)(Xb + (size_t)tb*HDIM);
  float4 v = src[threadIdx.x];
  ushort4 o; o.x=f2bf(v.x); o.y=f2bf(v.y); o.z=f2bf(v.z); o.w=f2bf(v.w);
  dst[threadIdx.x] = o;
}

// ---------------- big MFMA GEMM: C = act(A@B^T + bias) ----------------
// act: 0 = fp32 store, 1 = tanh fp32 store, 2 = bf16 store
__global__ __launch_bounds__(256) void gemm_mfma_bt(
    const ushort* __restrict__ A0, const ushort* __restrict__ A1, int lda, int KSPLIT,
    const ushort* __restrict__ B, int ldb,
    const float* __restrict__ bias,
    float* __restrict__ C, int ldc, int K, int act){
  __shared__ ushort As[64][40];
  __shared__ ushort Bs[64][40];
  const int bm = blockIdx.y*64, bn = blockIdx.x*64;
  const int tid = threadIdx.x, w = tid>>6, lane = tid&63;
  const int quad = lane>>4, l16 = lane&15;
  const int mh = (w>>1)*32, nh = (w&1)*32;
  const int arow = tid>>2, aseg = (tid&3)*8;
  f32x4 acc[2][2];
  #pragma unroll
  for(int i=0;i<2;i++)
    #pragma unroll
    for(int j=0;j<2;j++) acc[i][j] = (f32x4){0.f,0.f,0.f,0.f};

  for(int k0=0;k0<K;k0+=32){
    int gk = k0 + aseg;
    const ushort* ap = (gk < KSPLIT) ? (A0 + (size_t)(bm+arow)*lda + gk)
                                     : (A1 + (size_t)(bm+arow)*lda + (gk - KSPLIT));
    *(float4*)&As[arow][aseg] = *(const float4*)ap;
    *(float4*)&Bs[arow][aseg] = *(const float4*)(B + (size_t)(bn+arow)*ldb + k0 + aseg);
    __syncthreads();
    short8 a0 = *(const short8*)&As[mh + l16][quad*8];
    short8 a1 = *(const short8*)&As[mh + 16 + l16][quad*8];
    short8 b0 = *(const short8*)&Bs[nh + l16][quad*8];
    short8 b1 = *(const short8*)&Bs[nh + 16 + l16][quad*8];
    acc[0][0] = MFMA16(a0, b0, acc[0][0]);
    acc[0][1] = MFMA16(a0, b1, acc[0][1]);
    acc[1][0] = MFMA16(a1, b0, acc[1][0]);
    acc[1][1] = MFMA16(a1, b1, acc[1][1]);
    __syncthreads();
  }
  #pragma unroll
  for(int mi=0;mi<2;mi++){
    #pragma unroll
    for(int r=0;r<4;r++){
      int row = bm + mh + mi*16 + quad*4 + r;
      #pragma unroll
      for(int ni=0;ni<2;ni++){
        int col = bn + nh + ni*16 + l16;
        float v = acc[mi][ni][r];
        if(bias) v += bias[col];
        if(act==1) v = tanhf(v);
        if(act==2) ((ushort*)C)[(size_t)row*ldc + col] = f2bf(v);
        else       C[(size_t)row*ldc + col] = v;
      }
    }
  }
}

// ---------------- persistent LSTM scan ----------------
// 256 blocks, 1/CU. Block owns cols j0..j0+3 of h (both layers) and the 16
// weight rows {g*1024+j0+jj} of Whh0 and [Wih1|Whh1] in LDS for all 64 steps.
// Device sync: flag-array barrier (per-block store + wave-0 poll; no RMW
// contention — a single shared counter costs ~25 us/step in RMW serialization).
__global__ void lstm_persistent(
    const ushort* __restrict__ Whh0b,   // [4096][1024] bf16
    const ushort* __restrict__ Wih1b,   // [4096][1024]
    const ushort* __restrict__ Whh1b,   // [4096][1024]
    const float*  __restrict__ G0,      // [T*32][4096] fp32 (bias0 folded)
    const float*  __restrict__ bias1c,  // [4096]
    const float*  __restrict__ c0in,    // [2][32][1024]
    ushort* __restrict__ hbuf,          // [4][32][1024]: l0p0,l0p1,l1p0,l1p1
    ushort* __restrict__ inp_bf,        // [T*32][1024]
    float*  __restrict__ outstate,      // h[2][32][1024] then c[2][32][1024]
    int* __restrict__ flags){           // [256]
  extern __shared__ char smem[];
  ushort (*W0s)[1032] = (ushort(*)[1032])smem;                    // 33024 B
  ushort (*W1s)[2056] = (ushort(*)[2056])(smem + 33024);          // 65792 B
  float (*gred)[32][17] = (float(*)[32][17])(smem + 98816);       // 8704 B
  float (*cloc)[32][4]  = (float(*)[32][4]) (smem + 107520);      // 1024 B

  const int tid = threadIdx.x, w = tid>>6, lane = tid&63;
  const int quad = lane>>4, l16 = lane&15;
  const int blk = blockIdx.x;
  const int j0 = blk*4;

  // ---- load weight slices into LDS (held for all 64 steps) ----
  {
    int r = tid>>4, seg = tid&15;                       // 16 rows x 16 segments
    int wr = (r>>2)*1024 + j0 + (r&3);                  // gate-major weight row
    const ushort* s0 = Whh0b + (size_t)wr*1024 + seg*64;
    const ushort* s1 = Wih1b + (size_t)wr*1024 + seg*64;
    const ushort* s2 = Whh1b + (size_t)wr*1024 + seg*64;
    #pragma unroll
    for(int u=0; u<64; u+=8){
      *(short8*)&W0s[r][seg*64+u]       = *(const short8*)(s0+u);
      *(short8*)&W1s[r][seg*64+u]       = *(const short8*)(s1+u);
      *(short8*)&W1s[r][1024+seg*64+u]  = *(const short8*)(s2+u);
    }
  }
  if(tid < 128){
    int b = tid>>2, jj = tid&3;
    cloc[0][b][jj] = c0in[b*1024 + j0 + jj];
    cloc[1][b][jj] = c0in[32768 + b*1024 + j0 + jj];
  }
  // loop-invariant bias1 in registers (cell threads only)
  float2 pbI={0,0}, pbF={0,0}, pbG={0,0}, pbO={0,0};
  if(tid < 64){
    const float* br = bias1c + j0 + (tid&1)*2;
    pbI = *(const float2*)(br);
    pbF = *(const float2*)(br+1024);
    pbG = *(const float2*)(br+2048);
    pbO = *(const float2*)(br+3072);
  }
  __syncthreads();

  ushort* hb0[2] = { hbuf,            hbuf + 32768 };
  ushort* hb1[2] = { hbuf + 2*32768,  hbuf + 3*32768 };

  for(int t=0; t<TDIM; t++){
    int p = t&1, q = p^1;
    // prefetch this step's G0 slice into registers (hides L3 latency under MFMA)
    float2 pgI={0,0}, pgF={0,0}, pgG={0,0}, pgO={0,0};
    if(tid < 64){
      const float* g0r = G0 + (size_t)(t*32+(tid>>1))*4096 + j0 + (tid&1)*2;
      pgI = *(const float2*)(g0r);
      pgF = *(const float2*)(g0r+1024);
      pgG = *(const float2*)(g0r+2048);
      pgO = *(const float2*)(g0r+3072);
    }
    // ================= phase 0: layer 0 =================
    {
      const ushort* hsrc = hb0[p];
      f32x4 acc0 = {0,0,0,0}, acc1 = {0,0,0,0};
      int kbase = w*256;
      #pragma unroll
      for(int kc=0;kc<8;kc++){
        int k = kbase + kc*32 + quad*8;
        short8 bfrag = *(const short8*)&W0s[l16][k];
        short8 af0 = *(const short8*)(hsrc + (size_t)l16*1024 + k);
        short8 af1 = *(const short8*)(hsrc + (size_t)(l16+16)*1024 + k);
        acc0 = MFMA16(af0, bfrag, acc0);
        acc1 = MFMA16(af1, bfrag, acc1);
      }
      #pragma unroll
      for(int r=0;r<4;r++){
        gred[w][quad*4+r][l16]    = acc0[r];
        gred[w][16+quad*4+r][l16] = acc1[r];
      }
      __syncthreads();
      if(tid < 64){
        int b = tid>>1, j2 = (tid&1)*2;
        ushort hv[2];
        #pragma unroll
        for(int u=0;u<2;u++){
          int jj = j2+u;
          float gi = u ? pgI.y : pgI.x;
          float gf = u ? pgF.y : pgF.x;
          float gg = u ? pgG.y : pgG.x;
          float go = u ? pgO.y : pgO.x;
          #pragma unroll
          for(int ww=0;ww<4;ww++){
            gi += gred[ww][b][jj];    gf += gred[ww][b][4+jj];
            gg += gred[ww][b][8+jj];  go += gred[ww][b][12+jj];
          }
          float c = cloc[0][b][jj];
          float c1 = sigm(gf)*c + sigm(gi)*tanhf(gg);
          float h1 = sigm(go)*tanhf(c1);
          cloc[0][b][jj] = c1;
          hv[u] = f2bf(h1);
          if(t==TDIM-1){
            outstate[b*1024 + j0 + jj] = h1;          // hT layer0
            outstate[65536 + b*1024 + j0 + jj] = c1;  // cT layer0
          }
        }
        uint pk = (uint)hv[0] | ((uint)hv[1] << 16);
        __hip_atomic_store((uint*)(hb0[q] + b*1024 + j0 + j2), pk,
                           __ATOMIC_RELAXED, __HIP_MEMORY_SCOPE_AGENT);
      }
    }
    // ================= device barrier (flag array, no RMW) =================
    __syncthreads();                       // drains this block's stores
    if(tid==0){
      __threadfence();
      __hip_atomic_store(&flags[blk], t+1, __ATOMIC_RELEASE, __HIP_MEMORY_SCOPE_AGENT);
    }
    if(tid < 64){
      const int base = tid*4;
      const int target = t+1;
      while(true){
        int v0 = __hip_atomic_load(&flags[base+0], __ATOMIC_RELAXED, __HIP_MEMORY_SCOPE_AGENT);
        int v1 = __hip_atomic_load(&flags[base+1], __ATOMIC_RELAXED, __HIP_MEMORY_SCOPE_AGENT);
        int v2 = __hip_atomic_load(&flags[base+2], __ATOMIC_RELAXED, __HIP_MEMORY_SCOPE_AGENT);
        int v3 = __hip_atomic_load(&flags[base+3], __ATOMIC_RELAXED, __HIP_MEMORY_SCOPE_AGENT);
        int mn = min(min(v0,v1),min(v2,v3));
        if(__all(mn >= target)) break;
        __builtin_amdgcn_s_sleep(2);
      }
      __threadfence();                     // invalidate caches before reading peers' h
    }
    __syncthreads();
    // ================= phase 1: layer 1 (K=2048: [h0'; h1]) =================
    {
      f32x4 acc0 = {0,0,0,0}, acc1 = {0,0,0,0};
      int kbase = w*512;
      #pragma unroll
      for(int kc=0;kc<16;kc++){
        int k = kbase + kc*32 + quad*8;
        short8 bfrag = *(const short8*)&W1s[l16][k];
        const ushort* hsrc = (k < 1024) ? (hb0[q] + k) : (hb1[p] + (k-1024));
        short8 af0 = *(const short8*)(hsrc + (size_t)l16*1024);
        short8 af1 = *(const short8*)(hsrc + (size_t)(l16+16)*1024);
        acc0 = MFMA16(af0, bfrag, acc0);
        acc1 = MFMA16(af1, bfrag, acc1);
      }
      #pragma unroll
      for(int r=0;r<4;r++){
        gred[w][quad*4+r][l16]    = acc0[r];
        gred[w][16+quad*4+r][l16] = acc1[r];
      }
      __syncthreads();
      if(tid < 64){
        int b = tid>>1, j2 = (tid&1)*2;
        ushort hv[2];
        #pragma unroll
        for(int u=0;u<2;u++){
          int jj = j2+u;
          float gi = u ? pbI.y : pbI.x;
          float gf = u ? pbF.y : pbF.x;
          float gg = u ? pbG.y : pbG.x;
          float go = u ? pbO.y : pbO.x;
          #pragma unroll
          for(int ww=0;ww<4;ww++){
            gi += gred[ww][b][jj];    gf += gred[ww][b][4+jj];
            gg += gred[ww][b][8+jj];  go += gred[ww][b][12+jj];
          }
          float c = cloc[1][b][jj];
          float c1 = sigm(gf)*c + sigm(gi)*tanhf(gg);
          float h1 = sigm(go)*tanhf(c1);
          cloc[1][b][jj] = c1;
          hv[u] = f2bf(h1);
          inp_bf[(size_t)(t*32+b)*1024 + j0 + jj] = hv[u];
          if(t==TDIM-1){
            outstate[32768 + b*1024 + j0 + jj] = h1;          // hT layer1
            outstate[65536 + 32768 + b*1024 + j0 + jj] = c1;  // cT layer1
          }
        }
        uint pk = (uint)hv[0] | ((uint)hv[1] << 16);
        __hip_atomic_store((uint*)(hb1[q] + b*1024 + j0 + j2), pk,
                           __ATOMIC_RELAXED, __HIP_MEMORY_SCOPE_AGENT);
      }
      __syncthreads();                    // gred reused by next step's phase0
    }
  }
}

// ---------------- MFMA attention: block = (t-chunk of 16, b) ----------------
__global__ __launch_bounds__(256) void attn_mfma(
    const ushort* __restrict__ gamma_bf, // [2048][1024] rows t*32+b
    const ushort* __restrict__ ctxb,     // [32][64][1024] bf16
    const ushort* __restrict__ ctxT,     // [32][1024][64] bf16
    ushort* __restrict__ ctx_out){       // [2048][1024] bf16
  const int b = blockIdx.y, t0 = blockIdx.x*16;
  const int tid = threadIdx.x, w = tid>>6, lane = tid&63;
  const int quad = lane>>4, l16 = lane&15;
  __shared__ float S[16][68];
  __shared__ ushort Pb[16][72];
  {
    f32x4 acc = {0,0,0,0};
    const ushort* arow = gamma_bf + ((size_t)(t0+l16)*32 + b)*1024;
    const ushort* brow = ctxb + ((size_t)b*SDIM + w*16 + l16)*1024;
    #pragma unroll 8
    for(int kc=0;kc<32;kc++){
      short8 af = *(const short8*)(arow + kc*32 + quad*8);
      short8 bf = *(const short8*)(brow + kc*32 + quad*8);
      acc = MFMA16(af, bf, acc);
    }
    #pragma unroll
    for(int r=0;r<4;r++) S[quad*4+r][w*16+l16] = acc[r];
  }
  __syncthreads();
  if(tid < 16){
    float mx = -1e30f;
    for(int s=0;s<SDIM;s++) mx = fmaxf(mx, S[tid][s]);
    float sum = 0.f;
    for(int s=0;s<SDIM;s++) sum += expf(S[tid][s]-mx);
    float inv = 1.f/sum;
    for(int s=0;s<SDIM;s++) Pb[tid][s] = f2bf(expf(S[tid][s]-mx)*inv);
  }
  __syncthreads();
  const ushort* bbase = ctxT + ((size_t)b*HDIM + w*256)*SDIM;
  for(int nt=0; nt<16; nt++){
    f32x4 acc = {0,0,0,0};
    #pragma unroll
    for(int kc=0;kc<2;kc++){
      short8 af = *(const short8*)&Pb[l16][kc*32 + quad*8];
      short8 bf = *(const short8*)(bbase + (size_t)(nt*16+l16)*SDIM + kc*32 + quad*8);
      acc = MFMA16(af, bf, acc);
    }
    int n = w*256 + nt*16 + l16;
    #pragma unroll
    for(int r=0;r<4;r++){
      int t = t0 + quad*4 + r;
      ctx_out[((size_t)t*32 + b)*1024 + n] = f2bf(acc[r]);
    }
  }
}

extern "C" void kernel_launch(void* const* d_in, const int* in_sizes, int n_in,
                              void* d_out, int out_size, void* d_ws, size_t ws_size,
                              hipStream_t stream){
  const int*   tokens   = (const int*)  d_in[0];
  const float* h0       = (const float*)d_in[1];
  const float* c0       = (const float*)d_in[2];
  const float* contexts = (const float*)d_in[3];
  const float* emb      = (const float*)d_in[4];
  const float* W_ih     = (const float*)d_in[5];   // [2,4H,H]
  const float* W_hh     = (const float*)d_in[6];
  const float* b_ih     = (const float*)d_in[7];   // [2,4H]
  const float* b_hh     = (const float*)d_in[8];
  const float* W_in     = (const float*)d_in[9];   // [H,H]
  const float* b_in     = (const float*)d_in[10];
  const float* W_out    = (const float*)d_in[11];  // [H,2H]
  const float* b_out    = (const float*)d_in[12];

  float* out = (float*)d_out;
  const int TB = TDIM*BDIM;                        // 2048

  // ---- workspace layout ----
  char* wp = (char*)d_ws;
  float* G0      = (float*)wp;  wp += (size_t)TB*4*HDIM*4;          // 33.5 MB
  float* bias0c  = (float*)wp;  wp += 4096*4;
  float* bias1c  = (float*)wp;  wp += 4096*4;
  int*   flags   = (int*)wp;    wp += 1024;                         // 256 ints
  ushort* X_bf   = (ushort*)wp; wp += (size_t)TB*HDIM*2;
  ushort* Wih0b  = (ushort*)wp; wp += (size_t)4*HDIM*HDIM*2;
  ushort* Whh0b  = (ushort*)wp; wp += (size_t)4*HDIM*HDIM*2;
  ushort* Wih1b  = (ushort*)wp; wp += (size_t)4*HDIM*HDIM*2;
  ushort* Whh1b  = (ushort*)wp; wp += (size_t)4*HDIM*HDIM*2;
  ushort* Winb   = (ushort*)wp; wp += (size_t)HDIM*HDIM*2;
  ushort* Woutb  = (ushort*)wp; wp += (size_t)HDIM*2*HDIM*2;
  ushort* inp_bf = (ushort*)wp; wp += (size_t)TB*HDIM*2;
  ushort* hbuf   = (ushort*)wp; wp += (size_t)4*BDIM*HDIM*2;
  ushort* ctxb_bf= (ushort*)wp; wp += (size_t)BDIM*SDIM*HDIM*2;
  ushort* ctxT_bf= (ushort*)wp; wp += (size_t)BDIM*SDIM*HDIM*2;
  ushort* gammaB = (ushort*)G0;                                     // overlay
  ushort* ctx_bf = X_bf;                                            // overlay

  // ---- prep ----
  init_state_kernel<<<256,256,0,stream>>>(h0, hbuf);
  bar_init_kernel<<<1,256,0,stream>>>(flags);
  cast_kernel<<<4096,256,0,stream>>>(W_ih,                       Wih0b, 4*HDIM*HDIM/4);
  cast_kernel<<<4096,256,0,stream>>>(W_hh,                       Whh0b, 4*HDIM*HDIM/4);
  cast_kernel<<<4096,256,0,stream>>>(W_ih + (size_t)4*HDIM*HDIM, Wih1b, 4*HDIM*HDIM/4);
  cast_kernel<<<4096,256,0,stream>>>(W_hh + (size_t)4*HDIM*HDIM, Whh1b, 4*HDIM*HDIM/4);
  cast_kernel<<<1024,256,0,stream>>>(W_in,  Winb,  HDIM*HDIM/4);
  cast_kernel<<<2048,256,0,stream>>>(W_out, Woutb, HDIM*2*HDIM/4);
  cast_kernel<<<2048,256,0,stream>>>(contexts, ctxb_bf, BDIM*SDIM*HDIM/4);
  transpose_ctx_kernel<<<dim3(16,32),256,0,stream>>>(contexts, ctxT_bf);
  bias_kernel<<<16,256,0,stream>>>(b_ih, b_hh, bias0c, bias1c);
  embed_kernel<<<TB,256,0,stream>>>(tokens, emb, X_bf);

  // ---- G0 = X @ Wih0^T + (b_ih0+b_hh0)  [2048,4096] fp32 ----
  gemm_mfma_bt<<<dim3(4*HDIM/64, TB/64),256,0,stream>>>(
      X_bf, X_bf, HDIM, HDIM, Wih0b, HDIM, bias0c, G0, 4*HDIM, HDIM, 0);

  // ---- persistent LSTM scan (1 dispatch, 64 steps) ----
  lstm_persistent<<<NBLK,256,108544,stream>>>(
      Whh0b, Wih1b, Whh1b, G0, bias1c, c0,
      hbuf, inp_bf, out + (size_t)TB*HDIM, flags);

  // ---- gamma = inp @ W_in^T + b_in -> bf16 (overlays G0) ----
  gemm_mfma_bt<<<dim3(HDIM/64, TB/64),256,0,stream>>>(
      inp_bf, inp_bf, HDIM, HDIM, Winb, HDIM, b_in, (float*)gammaB, HDIM, HDIM, 2);

  // ---- attention (MFMA) ----
  attn_mfma<<<dim3(4,32),256,0,stream>>>(gammaB, ctxb_bf, ctxT_bf, ctx_bf);

  // ---- out = tanh([ctx|inp] @ W_out^T + b_out) -> d_out ----
  gemm_mfma_bt<<<dim3(HDIM/64, TB/64),256,0,stream>>>(
      ctx_bf, inp_bf, HDIM, HDIM, Woutb, 2*HDIM, b_out, out, HDIM, 2*HDIM, 1);
}

// Round 7
// 1795.207 us; speedup vs baseline: 13.2276x; 1.0387x over previous
//
#include <hip/hip_runtime.h>
#include <hip/hip_bf16.h>

#define HDIM 1024
#define BDIM 32
#define TDIM 64
#define SDIM 64
#define NBLK 256

typedef __attribute__((ext_vector_type(8))) short short8;
typedef __attribute__((ext_vector_type(4))) float f32x4;
typedef unsigned short ushort;
typedef unsigned int uint;

__device__ __forceinline__ float sigm(float x){ return 1.f/(1.f+expf(-x)); }
__device__ __forceinline__ ushort f2bf(float x){
  uint u = __float_as_uint(x);
  u = (u + 0x7FFF + ((u>>16)&1)) >> 16;   // RNE
  return (ushort)u;
}
#define MFMA16(a,b,c) __builtin_amdgcn_mfma_f32_16x16x32_bf16((a),(b),(c),0,0,0)
#define ALD(p)     __hip_atomic_load((p), __ATOMIC_RELAXED, __HIP_MEMORY_SCOPE_AGENT)
#define AST(p,v)   __hip_atomic_store((p),(v), __ATOMIC_RELAXED, __HIP_MEMORY_SCOPE_AGENT)

// ---------------- init: bf16 h seeds (parity 0 for both layers) ----------------
__global__ void init_state_kernel(const float* __restrict__ h0,
                                  ushort* __restrict__ hbuf){ // [4][32768]: h0p0,h0p1,h1p0,h1p1
  int i = blockIdx.x*256 + threadIdx.x;       // 0..65535
  int l = i >> 15, r = i & 32767;
  hbuf[(size_t)(l*2)*32768 + r] = f2bf(h0[i]);
}

__global__ void bar_init_kernel(int* flags){ flags[threadIdx.x] = 0; }

// ---------------- fp32 -> bf16 cast (vector x4) ----------------
__global__ void cast_kernel(const float* __restrict__ src, ushort* __restrict__ dst, int n4){
  int i = blockIdx.x*256 + threadIdx.x;
  if(i < n4){
    float4 v = ((const float4*)src)[i];
    ushort4 o; o.x=f2bf(v.x); o.y=f2bf(v.y); o.z=f2bf(v.z); o.w=f2bf(v.w);
    ((ushort4*)dst)[i] = o;
  }
}

// ---------------- contexts transpose: [32][64][1024] f32 -> [32][1024][64] bf16 ----
__global__ void transpose_ctx_kernel(const float* __restrict__ ctx, ushort* __restrict__ ctxT){
  int b = blockIdx.y;
  int n = blockIdx.x*64 + (threadIdx.x & 63);
  int s0 = (threadIdx.x >> 6) * 16;
  for(int s=s0; s<s0+16; s++){
    float v = ctx[((size_t)b*SDIM + s)*HDIM + n];
    ctxT[((size_t)b*HDIM + n)*SDIM + s] = f2bf(v);
  }
}

// ---------------- combined biases ----------------
__global__ void bias_kernel(const float* __restrict__ b_ih, const float* __restrict__ b_hh,
                            float* __restrict__ bias0, float* __restrict__ bias1){
  int i = blockIdx.x*256 + threadIdx.x;   // 0..4095
  bias0[i] = b_ih[i] + b_hh[i];
  bias1[i] = b_ih[4096+i] + b_hh[4096+i];
}

// ---------------- embedding gather + bf16 cast ----------------
__global__ void embed_kernel(const int* __restrict__ tokens,
                             const float* __restrict__ emb,
                             ushort* __restrict__ Xb){
  int tb = blockIdx.x;
  int tok = tokens[tb];
  const float4* src = (const float4*)(emb + (size_t)tok*HDIM);
  ushort4* dst = (ushort4*)(Xb + (size_t)tb*HDIM);
  float4 v = src[threadIdx.x];
  ushort4 o; o.x=f2bf(v.x); o.y=f2bf(v.y); o.z=f2bf(v.z); o.w=f2bf(v.w);
  dst[threadIdx.x] = o;
}

// ---------------- big MFMA GEMM: C = act(A@B^T + bias) ----------------
// act: 0 = fp32 store, 1 = tanh fp32 store, 2 = bf16 store
__global__ __launch_bounds__(256) void gemm_mfma_bt(
    const ushort* __restrict__ A0, const ushort* __restrict__ A1, int lda, int KSPLIT,
    const ushort* __restrict__ B, int ldb,
    const float* __restrict__ bias,
    float* __restrict__ C, int ldc, int K, int act){
  __shared__ ushort As[64][40];
  __shared__ ushort Bs[64][40];
  const int bm = blockIdx.y*64, bn = blockIdx.x*64;
  const int tid = threadIdx.x, w = tid>>6, lane = tid&63;
  const int quad = lane>>4, l16 = lane&15;
  const int mh = (w>>1)*32, nh = (w&1)*32;
  const int arow = tid>>2, aseg = (tid&3)*8;
  f32x4 acc[2][2];
  #pragma unroll
  for(int i=0;i<2;i++)
    #pragma unroll
    for(int j=0;j<2;j++) acc[i][j] = (f32x4){0.f,0.f,0.f,0.f};

  for(int k0=0;k0<K;k0+=32){
    int gk = k0 + aseg;
    const ushort* ap = (gk < KSPLIT) ? (A0 + (size_t)(bm+arow)*lda + gk)
                                     : (A1 + (size_t)(bm+arow)*lda + (gk - KSPLIT));
    *(float4*)&As[arow][aseg] = *(const float4*)ap;
    *(float4*)&Bs[arow][aseg] = *(const float4*)(B + (size_t)(bn+arow)*ldb + k0 + aseg);
    __syncthreads();
    short8 a0 = *(const short8*)&As[mh + l16][quad*8];
    short8 a1 = *(const short8*)&As[mh + 16 + l16][quad*8];
    short8 b0 = *(const short8*)&Bs[nh + l16][quad*8];
    short8 b1 = *(const short8*)&Bs[nh + 16 + l16][quad*8];
    acc[0][0] = MFMA16(a0, b0, acc[0][0]);
    acc[0][1] = MFMA16(a0, b1, acc[0][1]);
    acc[1][0] = MFMA16(a1, b0, acc[1][0]);
    acc[1][1] = MFMA16(a1, b1, acc[1][1]);
    __syncthreads();
  }
  #pragma unroll
  for(int mi=0;mi<2;mi++){
    #pragma unroll
    for(int r=0;r<4;r++){
      int row = bm + mh + mi*16 + quad*4 + r;
      #pragma unroll
      for(int ni=0;ni<2;ni++){
        int col = bn + nh + ni*16 + l16;
        float v = acc[mi][ni][r];
        if(bias) v += bias[col];
        if(act==1) v = tanhf(v);
        if(act==2) ((ushort*)C)[(size_t)row*ldc + col] = f2bf(v);
        else       C[(size_t)row*ldc + col] = v;
      }
    }
  }
}

// ---------------- skewed persistent LSTM scan ----------------
// r4-proven lockstep architecture (256 blocks, direct flag poll, threadfence
// pairs, parity double-buffers) + software-pipeline skew: phase p computes
// layer0 step p AND layer1 step p-1 -> ONE barrier per phase, 65 phases
// (r4: 128). Block owns 4 columns of h (both layers): 16 Whh0 rows + 16
// [Wih1|Whh1] rows in LDS for the whole scan.
__global__ void lstm_skew(
    const ushort* __restrict__ Whh0b,   // [4096][1024] bf16
    const ushort* __restrict__ Wih1b,   // [4096][1024]
    const ushort* __restrict__ Whh1b,   // [4096][1024]
    const float*  __restrict__ G0,      // [T*32][4096] fp32 (bias0 folded)
    const float*  __restrict__ bias1c,  // [4096]
    const float*  __restrict__ c0in,    // [2][32][1024]
    ushort* __restrict__ hbuf,          // [4][32768]: h0p0,h0p1,h1p0,h1p1
    ushort* __restrict__ inp_bf,        // [T*32][1024]
    float*  __restrict__ outstate,      // h[2][32][1024] then c[2][32][1024]
    int* __restrict__ flags){           // [256]
  extern __shared__ char smem[];
  ushort (*W0s)[1032]   = (ushort(*)[1032])smem;                   // 33024 B
  ushort (*W1s)[2056]   = (ushort(*)[2056])(smem + 33024);         // 65792 B
  float (*gred0)[32][17] = (float(*)[32][17])(smem + 98816);       // 8704 B
  float (*gred1)[32][17] = (float(*)[32][17])(smem + 107520);      // 8704 B
  float (*cloc0)[4]      = (float(*)[4])(smem + 116224);           // 512 B
  float (*cloc1)[4]      = (float(*)[4])(smem + 116736);           // 512 B

  const int tid = threadIdx.x, w = tid>>6, lane = tid&63;
  const int quad = lane>>4, l16 = lane&15;
  const int blk = blockIdx.x;
  const int j0 = blk*4;

  // ---- load weight slices into LDS (held for all phases) — r4 verbatim ----
  {
    int r = tid>>4, seg = tid&15;                       // 16 rows x 16 segments
    int wr = (r>>2)*1024 + j0 + (r&3);                  // gate-major weight row
    const ushort* s0 = Whh0b + (size_t)wr*1024 + seg*64;
    const ushort* s1 = Wih1b + (size_t)wr*1024 + seg*64;
    const ushort* s2 = Whh1b + (size_t)wr*1024 + seg*64;
    #pragma unroll
    for(int u=0; u<64; u+=8){
      *(short8*)&W0s[r][seg*64+u]       = *(const short8*)(s0+u);
      *(short8*)&W1s[r][seg*64+u]       = *(const short8*)(s1+u);
      *(short8*)&W1s[r][1024+seg*64+u]  = *(const short8*)(s2+u);
    }
  }
  if(tid < 128){
    int b = tid>>2, jj = tid&3;
    cloc0[b][jj] = c0in[b*1024 + j0 + jj];
    cloc1[b][jj] = c0in[32768 + b*1024 + j0 + jj];
  }
  // loop-invariant bias1 in registers (layer-1 cell threads: tid 64..127)
  float2 pbI={0,0}, pbF={0,0}, pbG={0,0}, pbO={0,0};
  if(tid >= 64 && tid < 128){
    const float* br = bias1c + j0 + ((tid-64)&1)*2;
    pbI = *(const float2*)(br);
    pbF = *(const float2*)(br+1024);
    pbG = *(const float2*)(br+2048);
    pbO = *(const float2*)(br+3072);
  }
  __syncthreads();

  ushort* h0b[2] = { hbuf,            hbuf + 32768 };
  ushort* h1b[2] = { hbuf + 65536,    hbuf + 98304 };

  for(int p=0; p<=TDIM; p++){
    const int par = p&1, nxt = par^1;
    // G0 prefetch for layer0 step p (overlaps MFMA issue)
    float2 pgI={0,0}, pgF={0,0}, pgG={0,0}, pgO={0,0};
    if(p < TDIM && tid < 64){
      const float* g0r = G0 + (size_t)(p*32+(tid>>1))*4096 + j0 + (tid&1)*2;
      pgI = *(const float2*)(g0r);
      pgF = *(const float2*)(g0r+1024);
      pgG = *(const float2*)(g0r+2048);
      pgO = *(const float2*)(g0r+3072);
    }
    // ---- MFMA layer0 step p: gates0 = h0(p) @ W0s^T (K-split across waves) ----
    if(p < TDIM){
      const ushort* hsrc = h0b[par];
      f32x4 acc0 = {0,0,0,0}, acc1 = {0,0,0,0};
      int kbase = w*256;
      #pragma unroll
      for(int kc=0;kc<8;kc++){
        int k = kbase + kc*32 + quad*8;
        short8 bfrag = *(const short8*)&W0s[l16][k];
        short8 af0 = *(const short8*)(hsrc + (size_t)l16*1024 + k);
        short8 af1 = *(const short8*)(hsrc + (size_t)(l16+16)*1024 + k);
        acc0 = MFMA16(af0, bfrag, acc0);
        acc1 = MFMA16(af1, bfrag, acc1);
      }
      #pragma unroll
      for(int r=0;r<4;r++){
        gred0[w][quad*4+r][l16]    = acc0[r];
        gred0[w][16+quad*4+r][l16] = acc1[r];
      }
    }
    // ---- MFMA layer1 step p-1: gates1 = [h0(p) | h1(p-1)] @ W1s^T ----
    if(p > 0){
      f32x4 acc0 = {0,0,0,0}, acc1 = {0,0,0,0};
      int kbase = w*512;
      #pragma unroll
      for(int kc=0;kc<16;kc++){
        int k = kbase + kc*32 + quad*8;
        short8 bfrag = *(const short8*)&W1s[l16][k];
        const ushort* hsrc = (k < 1024) ? (h0b[par] + k) : (h1b[nxt] + (k-1024));
        short8 af0 = *(const short8*)(hsrc + (size_t)l16*1024);
        short8 af1 = *(const short8*)(hsrc + (size_t)(l16+16)*1024);
        acc0 = MFMA16(af0, bfrag, acc0);
        acc1 = MFMA16(af1, bfrag, acc1);
      }
      #pragma unroll
      for(int r=0;r<4;r++){
        gred1[w][quad*4+r][l16]    = acc0[r];
        gred1[w][16+quad*4+r][l16] = acc1[r];
      }
    }
    __syncthreads();
    // ---- layer0 cell (wave 0) ----
    if(p < TDIM && tid < 64){
      int b = tid>>1, j2 = (tid&1)*2;
      ushort hv[2];
      #pragma unroll
      for(int u=0;u<2;u++){
        int jj = j2+u;
        float gi = u ? pgI.y : pgI.x;
        float gf = u ? pgF.y : pgF.x;
        float gg = u ? pgG.y : pgG.x;
        float go = u ? pgO.y : pgO.x;
        #pragma unroll
        for(int ww=0;ww<4;ww++){
          gi += gred0[ww][b][jj];    gf += gred0[ww][b][4+jj];
          gg += gred0[ww][b][8+jj];  go += gred0[ww][b][12+jj];
        }
        float c = cloc0[b][jj];
        float c1 = sigm(gf)*c + sigm(gi)*tanhf(gg);
        float h1 = sigm(go)*tanhf(c1);
        cloc0[b][jj] = c1;
        hv[u] = f2bf(h1);
        if(p==TDIM-1){
          outstate[b*1024 + j0 + jj] = h1;          // hT layer0
          outstate[65536 + b*1024 + j0 + jj] = c1;  // cT layer0
        }
      }
      uint pk = (uint)hv[0] | ((uint)hv[1] << 16);
      AST((uint*)(h0b[nxt] + b*1024 + j0 + j2), pk);
    }
    // ---- layer1 cell (wave 1), step t = p-1 ----
    if(p > 0 && tid >= 64 && tid < 128){
      int ct = tid-64;
      int b = ct>>1, j2 = (ct&1)*2;
      ushort hv[2];
      #pragma unroll
      for(int u=0;u<2;u++){
        int jj = j2+u;
        float gi = u ? pbI.y : pbI.x;
        float gf = u ? pbF.y : pbF.x;
        float gg = u ? pbG.y : pbG.x;
        float go = u ? pbO.y : pbO.x;
        #pragma unroll
        for(int ww=0;ww<4;ww++){
          gi += gred1[ww][b][jj];    gf += gred1[ww][b][4+jj];
          gg += gred1[ww][b][8+jj];  go += gred1[ww][b][12+jj];
        }
        float c = cloc1[b][jj];
        float c1 = sigm(gf)*c + sigm(gi)*tanhf(gg);
        float h1 = sigm(go)*tanhf(c1);
        cloc1[b][jj] = c1;
        hv[u] = f2bf(h1);
        inp_bf[(size_t)((p-1)*32+b)*1024 + j0 + jj] = hv[u];
        if(p==TDIM){
          outstate[32768 + b*1024 + j0 + jj] = h1;          // hT layer1
          outstate[98304 + b*1024 + j0 + jj] = c1;          // cT layer1
        }
      }
      uint pk = (uint)hv[0] | ((uint)hv[1] << 16);
      AST((uint*)(h1b[par] + b*1024 + j0 + j2), pk);
    }
    if(p == TDIM) break;                 // last phase: kernel end flushes
    // ---- barrier (r4-proven: flag array + direct poll + threadfence pair) ----
    __syncthreads();                     // drains h stores + gred reuse
    if(tid==0){ __threadfence(); AST(&flags[blk], p+1); }
    if(tid < 64){
      const int base = tid*4;
      const int target = p+1;
      while(true){
        int v0 = ALD(&flags[base+0]);
        int v1 = ALD(&flags[base+1]);
        int v2 = ALD(&flags[base+2]);
        int v3 = ALD(&flags[base+3]);
        int mn = min(min(v0,v1),min(v2,v3));
        if(__all(mn >= target)) break;
        __builtin_amdgcn_s_sleep(2);
      }
      __threadfence();                   // invalidate caches before reading peers' h
    }
    __syncthreads();
  }
}

// ---------------- MFMA attention: block = (t-chunk of 16, b) ----------------
__global__ __launch_bounds__(256) void attn_mfma(
    const ushort* __restrict__ gamma_bf, // [2048][1024] rows t*32+b
    const ushort* __restrict__ ctxb,     // [32][64][1024] bf16
    const ushort* __restrict__ ctxT,     // [32][1024][64] bf16
    ushort* __restrict__ ctx_out){       // [2048][1024] bf16
  const int b = blockIdx.y, t0 = blockIdx.x*16;
  const int tid = threadIdx.x, w = tid>>6, lane = tid&63;
  const int quad = lane>>4, l16 = lane&15;
  __shared__ float S[16][68];
  __shared__ ushort Pb[16][72];
  {
    f32x4 acc = {0,0,0,0};
    const ushort* arow = gamma_bf + ((size_t)(t0+l16)*32 + b)*1024;
    const ushort* brow = ctxb + ((size_t)b*SDIM + w*16 + l16)*1024;
    #pragma unroll 8
    for(int kc=0;kc<32;kc++){
      short8 af = *(const short8*)(arow + kc*32 + quad*8);
      short8 bf = *(const short8*)(brow + kc*32 + quad*8);
      acc = MFMA16(af, bf, acc);
    }
    #pragma unroll
    for(int r=0;r<4;r++) S[quad*4+r][w*16+l16] = acc[r];
  }
  __syncthreads();
  if(tid < 16){
    float mx = -1e30f;
    for(int s=0;s<SDIM;s++) mx = fmaxf(mx, S[tid][s]);
    float sum = 0.f;
    for(int s=0;s<SDIM;s++) sum += expf(S[tid][s]-mx);
    float inv = 1.f/sum;
    for(int s=0;s<SDIM;s++) Pb[tid][s] = f2bf(expf(S[tid][s]-mx)*inv);
  }
  __syncthreads();
  const ushort* bbase = ctxT + ((size_t)b*HDIM + w*256)*SDIM;
  for(int nt=0; nt<16; nt++){
    f32x4 acc = {0,0,0,0};
    #pragma unroll
    for(int kc=0;kc<2;kc++){
      short8 af = *(const short8*)&Pb[l16][kc*32 + quad*8];
      short8 bf = *(const short8*)(bbase + (size_t)(nt*16+l16)*SDIM + kc*32 + quad*8);
      acc = MFMA16(af, bf, acc);
    }
    int n = w*256 + nt*16 + l16;
    #pragma unroll
    for(int r=0;r<4;r++){
      int t = t0 + quad*4 + r;
      ctx_out[((size_t)t*32 + b)*1024 + n] = f2bf(acc[r]);
    }
  }
}

extern "C" void kernel_launch(void* const* d_in, const int* in_sizes, int n_in,
                              void* d_out, int out_size, void* d_ws, size_t ws_size,
                              hipStream_t stream){
  const int*   tokens   = (const int*)  d_in[0];
  const float* h0       = (const float*)d_in[1];
  const float* c0       = (const float*)d_in[2];
  const float* contexts = (const float*)d_in[3];
  const float* emb      = (const float*)d_in[4];
  const float* W_ih     = (const float*)d_in[5];   // [2,4H,H]
  const float* W_hh     = (const float*)d_in[6];
  const float* b_ih     = (const float*)d_in[7];   // [2,4H]
  const float* b_hh     = (const float*)d_in[8];
  const float* W_in     = (const float*)d_in[9];   // [H,H]
  const float* b_in     = (const float*)d_in[10];
  const float* W_out    = (const float*)d_in[11];  // [H,2H]
  const float* b_out    = (const float*)d_in[12];

  float* out = (float*)d_out;
  const int TB = TDIM*BDIM;                        // 2048

  // ---- workspace layout ----
  char* wp = (char*)d_ws;
  float* G0      = (float*)wp;  wp += (size_t)TB*4*HDIM*4;          // 33.5 MB
  float* bias0c  = (float*)wp;  wp += 4096*4;
  float* bias1c  = (float*)wp;  wp += 4096*4;
  int*   flags   = (int*)wp;    wp += 1024;                         // 256 ints
  ushort* X_bf   = (ushort*)wp; wp += (size_t)TB*HDIM*2;
  ushort* Wih0b  = (ushort*)wp; wp += (size_t)4*HDIM*HDIM*2;
  ushort* Whh0b  = (ushort*)wp; wp += (size_t)4*HDIM*HDIM*2;
  ushort* Wih1b  = (ushort*)wp; wp += (size_t)4*HDIM*HDIM*2;
  ushort* Whh1b  = (ushort*)wp; wp += (size_t)4*HDIM*HDIM*2;
  ushort* Winb   = (ushort*)wp; wp += (size_t)HDIM*HDIM*2;
  ushort* Woutb  = (ushort*)wp; wp += (size_t)HDIM*2*HDIM*2;
  ushort* inp_bf = (ushort*)wp; wp += (size_t)TB*HDIM*2;
  ushort* hbuf   = (ushort*)wp; wp += (size_t)4*BDIM*HDIM*2;
  ushort* ctxb_bf= (ushort*)wp; wp += (size_t)BDIM*SDIM*HDIM*2;
  ushort* ctxT_bf= (ushort*)wp; wp += (size_t)BDIM*SDIM*HDIM*2;
  ushort* gammaB = (ushort*)G0;                                     // overlay
  ushort* ctx_bf = X_bf;                                            // overlay

  // ---- prep ----
  init_state_kernel<<<256,256,0,stream>>>(h0, hbuf);
  bar_init_kernel<<<1,256,0,stream>>>(flags);
  cast_kernel<<<4096,256,0,stream>>>(W_ih,                       Wih0b, 4*HDIM*HDIM/4);
  cast_kernel<<<4096,256,0,stream>>>(W_hh,                       Whh0b, 4*HDIM*HDIM/4);
  cast_kernel<<<4096,256,0,stream>>>(W_ih + (size_t)4*HDIM*HDIM, Wih1b, 4*HDIM*HDIM/4);
  cast_kernel<<<4096,256,0,stream>>>(W_hh + (size_t)4*HDIM*HDIM, Whh1b, 4*HDIM*HDIM/4);
  cast_kernel<<<1024,256,0,stream>>>(W_in,  Winb,  HDIM*HDIM/4);
  cast_kernel<<<2048,256,0,stream>>>(W_out, Woutb, HDIM*2*HDIM/4);
  cast_kernel<<<2048,256,0,stream>>>(contexts, ctxb_bf, BDIM*SDIM*HDIM/4);
  transpose_ctx_kernel<<<dim3(16,32),256,0,stream>>>(contexts, ctxT_bf);
  bias_kernel<<<16,256,0,stream>>>(b_ih, b_hh, bias0c, bias1c);
  embed_kernel<<<TB,256,0,stream>>>(tokens, emb, X_bf);

  // ---- G0 = X @ Wih0^T + (b_ih0+b_hh0)  [2048,4096] fp32 ----
  gemm_mfma_bt<<<dim3(4*HDIM/64, TB/64),256,0,stream>>>(
      X_bf, X_bf, HDIM, HDIM, Wih0b, HDIM, bias0c, G0, 4*HDIM, HDIM, 0);

  // ---- skewed persistent scan (1 dispatch, 65 phases) ----
  lstm_skew<<<NBLK,256,117248,stream>>>(
      Whh0b, Wih1b, Whh1b, G0, bias1c, c0,
      hbuf, inp_bf, out + (size_t)TB*HDIM, flags);

  // ---- gamma = inp @ W_in^T + b_in -> bf16 (overlays G0) ----
  gemm_mfma_bt<<<dim3(HDIM/64, TB/64),256,0,stream>>>(
      inp_bf, inp_bf, HDIM, HDIM, Winb, HDIM, b_in, (float*)gammaB, HDIM, HDIM, 2);

  // ---- attention (MFMA) ----
  attn_mfma<<<dim3(4,32),256,0,stream>>>(gammaB, ctxb_bf, ctxT_bf, ctx_bf);

  // ---- out = tanh([ctx|inp] @ W_out^T + b_out) -> d_out ----
  gemm_mfma_bt<<<dim3(HDIM/64, TB/64),256,0,stream>>>(
      ctx_bf, inp_bf, HDIM, HDIM, Woutb, 2*HDIM, b_out, out, HDIM, 2*HDIM, 1);
}